// Round 2
// baseline (1581.321 us; speedup 1.0000x reference)
//
#include <hip/hip_runtime.h>
#include <hip/hip_bf16.h>

// ---------------------------------------------------------------------------
// HeteroGNN forward on MI355X — round 7: big-tile GEMM + dispatch fusion.
//   NP=200000, NA=100000, E=1e6 per relation (3 rels), DIN=128,
//   HID=64 (2 heads x 32), L=2 layers, DOUT=64.
// vs round 6:
//   * gemm256: 256-row tile per block (4 waves x 64 rows) -> 4x MFMA work
//     per B-stage+barrier (was 64-row tiles, staging-overhead-bound).
//   * Two-job GEMM launches: xl+xr per rel, both input projections, both
//     output projections each fused into ONE dispatch.
//   * CSR build fused across the 3 relations: 1 hist, 3 scans, 1 scatter
//     (was 15 dispatches). deg is a 3-wide contiguous arena, one memset.
//   * ln_relu for paper+author fused into one dispatch.
//   * gat_dst: 8-edge pipeline (deg<=8: all gathers issue in the prime
//     phase before any compute -> full latency overlap for the Poisson(5)
//     majority). ~23 dispatches total (was ~45).
// Wire dtype auto-detected (fp32 vs bf16) from ln_scale (all-ones).
// ---------------------------------------------------------------------------

#define NPAPER  200000
#define NAUTHOR 100000
#define NEDGE   1000000

#define NB_E    3907      // ceil(NEDGE/256)
#define NB1_P   196       // ceil(NPAPER/1024)
#define NB1_A   98        // ceil(NAUTHOR/1024)
#define NB256_P 782       // ceil(NPAPER/256)
#define NB256_A 391       // ceil(NAUTHOR/256)

typedef __attribute__((ext_vector_type(8))) short short8;   // 8 x bf16 bits
typedef __attribute__((ext_vector_type(4))) float f32x4;

__device__ inline float b2f(__hip_bfloat16 v) { return __bfloat162float(v); }

__device__ inline short f2bs(float f) {        // fp32 -> bf16 bits (RNE)
    unsigned u = __float_as_uint(f);
    u += 0x7FFFu + ((u >> 16) & 1u);
    return (short)(u >> 16);
}

__device__ inline float wireF(const void* p, int i, int f32) {
    return f32 ? ((const float*)p)[i]
               : b2f(((const __hip_bfloat16*)p)[i]);
}

__device__ inline const int* sel3(int r, const int* a, const int* b, const int* c) {
    return r == 0 ? a : (r == 1 ? b : c);
}
__device__ inline int* sel3m(int r, int* a, int* b, int* c) {
    return r == 0 ? a : (r == 1 ? b : c);
}

__global__ void detect_mode(const unsigned* __restrict__ lns, int* __restrict__ flag) {
    if (threadIdx.x == 0 && blockIdx.x == 0)
        flag[0] = (lns[0] == 0x3F800000u) ? 1 : 0;   // 1 = fp32 wire
}

// ---------------------------------------------------------------------------
// GEMM: Y[row_off + 0..N, 0..64] = A[N,K] @ B[K,64] + bias, two jobs per
// launch (block ranges). 256-row tile per 256-thread block; each wave owns
// 64 rows (4 row-groups x 16), so K=64 gives 32 MFMAs per wave per stage.
// OUT_MODE: 0 = internal bf16, 2 = wire dtype (per flag).
// A_WIRE:   true = A is a wire tensor (dtype per flag), false = internal bf16.
// ---------------------------------------------------------------------------
template <int K, int OUT_MODE, bool A_WIRE>
__global__ __launch_bounds__(256) void gemm256(
    const void* __restrict__ A0v, const void* __restrict__ B0v, int b0_off,
    const void* __restrict__ bias0v, int bias0_off,
    void* __restrict__ Y0v, int N0, int row0_off, int nblk0,
    const void* __restrict__ A1v, const void* __restrict__ B1v, int b1_off,
    const void* __restrict__ bias1v, int bias1_off,
    void* __restrict__ Y1v, int N1, int row1_off,
    const int* __restrict__ flagp)
{
    const int f32 = flagp[0];
    int bid = blockIdx.x;
    const void* Av; const void* Bv; int b_off; const void* biasv; int bias_off;
    void* Yv; int N; int row_off;
    if (bid < nblk0) {
        Av = A0v; Bv = B0v; b_off = b0_off; biasv = bias0v; bias_off = bias0_off;
        Yv = Y0v; N = N0; row_off = row0_off;
    } else {
        bid -= nblk0;
        Av = A1v; Bv = B1v; b_off = b1_off; biasv = bias1v; bias_off = bias1_off;
        Yv = Y1v; N = N1; row_off = row1_off;
    }

    constexpr int SB = K + 8;
    __shared__ short Bs[64 * SB];
    __shared__ float sbias[64];

    const int tid = threadIdx.x;
    for (int idx = tid; idx < K * 64; idx += 256) {
        const int k = idx >> 6;                 // B is [K,64] row-major
        const int n = idx & 63;
        const short v = f32 ? f2bs(((const float*)Bv)[b_off + idx])
                            : ((const short*)Bv)[b_off + idx];
        Bs[n * SB + k] = v;
    }
    if (tid < 64)
        sbias[tid] = biasv ? wireF(biasv, bias_off + tid, f32) : 0.0f;
    __syncthreads();

    const int wave = tid >> 6;
    const int lane = tid & 63;
    const int l15  = lane & 15;
    const int quad = lane >> 4;
    const int row_base = bid * 256 + wave * 64;

    f32x4 acc[4][4] = {};                       // [row-group][col-group]

    int arow[4];
#pragma unroll
    for (int rg = 0; rg < 4; rg++) {
        int r = row_base + rg * 16 + l15;
        arow[rg] = (r < N) ? r : (N - 1);       // clamp; stores predicated
    }

#pragma unroll
    for (int kit = 0; kit < K / 32; kit++) {
        const int k0 = kit * 32 + quad * 8;
        short8 af[4];
#pragma unroll
        for (int rg = 0; rg < 4; rg++) {
            if (A_WIRE && f32) {
                const float* Ar = (const float*)Av + (size_t)arow[rg] * K + k0;
                const float4 a0 = *reinterpret_cast<const float4*>(Ar);
                const float4 a1 = *reinterpret_cast<const float4*>(Ar + 4);
                af[rg][0] = f2bs(a0.x); af[rg][1] = f2bs(a0.y);
                af[rg][2] = f2bs(a0.z); af[rg][3] = f2bs(a0.w);
                af[rg][4] = f2bs(a1.x); af[rg][5] = f2bs(a1.y);
                af[rg][6] = f2bs(a1.z); af[rg][7] = f2bs(a1.w);
            } else {
                af[rg] = *reinterpret_cast<const short8*>(
                    (const short*)Av + (size_t)arow[rg] * K + k0);
            }
        }
#pragma unroll
        for (int cg = 0; cg < 4; cg++) {
            const short8 bf = *reinterpret_cast<const short8*>(
                &Bs[(cg * 16 + l15) * SB + k0]);
#pragma unroll
            for (int rg = 0; rg < 4; rg++)
                acc[rg][cg] = __builtin_amdgcn_mfma_f32_16x16x32_bf16(
                    af[rg], bf, acc[rg][cg], 0, 0, 0);
        }
    }

#pragma unroll
    for (int rg = 0; rg < 4; rg++) {
#pragma unroll
        for (int cg = 0; cg < 4; cg++) {
            const int col = cg * 16 + l15;
            const float bv = sbias[col];
#pragma unroll
            for (int r = 0; r < 4; r++) {
                const int row = row_base + rg * 16 + quad * 4 + r;
                if (row < N) {
                    const float v = acc[rg][cg][r] + bv;
                    const size_t o = (size_t)(row + row_off) * 64 + col;
                    if (OUT_MODE == 0)
                        ((__hip_bfloat16*)Yv)[o] = __float2bfloat16(v);
                    else {
                        if (f32) ((float*)Yv)[o] = v;
                        else     ((__hip_bfloat16*)Yv)[o] = __float2bfloat16(v);
                    }
                }
            }
        }
    }
}

// ---------------------------------------------------------------------------
// CSR build, all 3 relations fused: histogram -> 2-level scan -> scatter.
// deg is a contiguous [3][NPAPER] arena (one memset).
// ---------------------------------------------------------------------------
__global__ __launch_bounds__(256) void hist3_k(
    const int* __restrict__ d0, const int* __restrict__ d1,
    const int* __restrict__ d2, int* __restrict__ deg)
{
    const int rel = blockIdx.x / NB_E;
    const int e   = (blockIdx.x % NB_E) * 256 + threadIdx.x;
    if (e < NEDGE) {
        const int* dst = sel3(rel, d0, d1, d2);
        atomicAdd(&deg[rel * NPAPER + dst[e]], 1);
    }
}

#define SCAN_TILE 1024
__global__ __launch_bounds__(256) void scan1_3k(
    const int* __restrict__ deg,
    int* __restrict__ rp0, int* __restrict__ rp1, int* __restrict__ rp2,
    int* __restrict__ blocksums)                 // [3][256]
{
    int bid = blockIdx.x, rel, n;
    if (bid < NB1_P)              { rel = 0; n = NPAPER; }
    else if (bid < NB1_P + NB1_A) { rel = 1; bid -= NB1_P; n = NAUTHOR; }
    else                          { rel = 2; bid -= NB1_P + NB1_A; n = NPAPER; }
    const int* dg = deg + rel * NPAPER;
    int* tile_ex  = sel3m(rel, rp0, rp1, rp2);
    int* bs       = blocksums + rel * 256;

    __shared__ int lds[256];
    const int t = threadIdx.x;
    const int base = bid * SCAN_TILE + t * 4;
    int v0 = (base + 0 < n) ? dg[base + 0] : 0;
    int v1 = (base + 1 < n) ? dg[base + 1] : 0;
    int v2 = (base + 2 < n) ? dg[base + 2] : 0;
    int v3 = (base + 3 < n) ? dg[base + 3] : 0;
    const int tsum = v0 + v1 + v2 + v3;
    lds[t] = tsum;
    __syncthreads();
    for (int off = 1; off < 256; off <<= 1) {
        const int x = (t >= off) ? lds[t - off] : 0;
        __syncthreads();
        lds[t] += x;
        __syncthreads();
    }
    int run = lds[t] - tsum;                    // exclusive prefix within tile
    if (t == 255) bs[bid] = lds[255];
    if (base + 0 < n) tile_ex[base + 0] = run;  run += v0;
    if (base + 1 < n) tile_ex[base + 1] = run;  run += v1;
    if (base + 2 < n) tile_ex[base + 2] = run;  run += v2;
    if (base + 3 < n) tile_ex[base + 3] = run;
}

__global__ __launch_bounds__(256) void scan2_3k(int* __restrict__ blocksums)
{
    const int rel = blockIdx.x;
    const int nb  = (rel == 1) ? NB1_A : NB1_P;
    int* bsa = blocksums + rel * 256;
    __shared__ int lds[256];
    const int t = threadIdx.x;
    const int v = (t < nb) ? bsa[t] : 0;
    lds[t] = v;
    __syncthreads();
    for (int off = 1; off < 256; off <<= 1) {
        const int x = (t >= off) ? lds[t - off] : 0;
        __syncthreads();
        lds[t] += x;
        __syncthreads();
    }
    if (t < nb) bsa[t] = lds[t] - v;
}

__global__ __launch_bounds__(256) void scan3_3k(
    int* __restrict__ rp0, int* __restrict__ rp1, int* __restrict__ rp2,
    int* __restrict__ of0, int* __restrict__ of1, int* __restrict__ of2,
    const int* __restrict__ blocksums)
{
    int bid = blockIdx.x, rel, n;
    if (bid < NB256_P)                { rel = 0; n = NPAPER; }
    else if (bid < NB256_P + NB256_A) { rel = 1; bid -= NB256_P; n = NAUTHOR; }
    else                              { rel = 2; bid -= NB256_P + NB256_A; n = NPAPER; }
    int* row_ptr  = sel3m(rel, rp0, rp1, rp2);
    int* offs     = sel3m(rel, of0, of1, of2);
    const int* bs = blocksums + rel * 256;

    const int i = bid * 256 + threadIdx.x;
    if (i < n) {
        const int v = row_ptr[i] + bs[i / SCAN_TILE];
        row_ptr[i] = v;
        offs[i] = v;
    }
    if (i == 0) row_ptr[n] = NEDGE;
}

__global__ __launch_bounds__(256) void scatter3_k(
    const int* __restrict__ s0, const int* __restrict__ s1, const int* __restrict__ s2,
    const int* __restrict__ d0, const int* __restrict__ d1, const int* __restrict__ d2,
    int* __restrict__ of0, int* __restrict__ of1, int* __restrict__ of2,
    int* __restrict__ c0, int* __restrict__ c1, int* __restrict__ c2)
{
    const int rel = blockIdx.x / NB_E;
    const int e   = (blockIdx.x % NB_E) * 256 + threadIdx.x;
    if (e < NEDGE) {
        const int* src = sel3(rel, s0, s1, s2);
        const int* dst = sel3(rel, d0, d1, d2);
        int* offs = sel3m(rel, of0, of1, of2);
        int* csr  = sel3m(rel, c0, c1, c2);
        const int p = atomicAdd(&offs[dst[e]], 1);
        csr[p] = src[e];
    }
}

// ---------------------------------------------------------------------------
// GATv2 aggregation, wave per dst node, lane = channel (head = c>>5).
// Round 7: 8 edges/iter (8 interleaved reduce chains) + next-oct prefetch.
// For deg<=8 (Poisson(5) majority) ALL gathers issue in the prime phase
// before any compute -> maximal load overlap, single pass, no prefetch.
// MODE 0: nw[d] = bias + result (bias-only for deg-0 rows)
// MODE 1: nw[d] += result (skip deg-0)
// ---------------------------------------------------------------------------
template <int MODE>
__global__ __launch_bounds__(256) void gat_dst(
    const int* __restrict__ row_ptr, const int* __restrict__ csr_src,
    const __hip_bfloat16* __restrict__ xl, const __hip_bfloat16* __restrict__ xr,
    const void* __restrict__ att, int att_off,
    const void* __restrict__ b1, int off1,
    const void* __restrict__ b2, int off2,    // b2 may be null (MODE 0 only)
    float* __restrict__ nw, int Nd, const int* __restrict__ flagp)
{
    __shared__ float satt[64];
    __shared__ float sbias[64];
    if (threadIdx.x < 64) {
        const int f32 = flagp[0];
        satt[threadIdx.x] = wireF(att, att_off + threadIdx.x, f32);
        if (MODE == 0) {
            float bv = wireF(b1, off1 + threadIdx.x, f32);
            if (b2) bv += wireF(b2, off2 + threadIdx.x, f32);
            sbias[threadIdx.x] = bv;
        }
    }
    __syncthreads();

    const int d = blockIdx.x * 4 + (threadIdx.x >> 6);
    const int c = threadIdx.x & 63;
    if (d >= Nd) return;
    const int beg = row_ptr[d];
    const int end = row_ptr[d + 1];
    const size_t dbase = (size_t)d * 64 + c;

    if (beg == end) {                     // no incident edges
        if (MODE == 0) nw[dbase] = sbias[c];
        return;
    }

    const float xrc  = b2f(xr[dbase]);
    const float attc = satt[c];
    float acc = 0.0f, den = 0.0f;

    int chunk = beg;
    while (chunk < end) {
        const int cend = (chunk + 64 < end) ? (chunk + 64) : end;
        const int n    = cend - chunk;               // 1..64 edges this chunk
        // cooperative index load: lane c holds csr_src[chunk + c] (clamped)
        const int lidx = csr_src[chunk + ((c < n) ? c : 0)];

        // ---- 8-deep pipeline over the chunk ----
        float x[8];
#pragma unroll
        for (int k = 0; k < 8; k++) {
            const int s = __shfl(lidx, k, 64);
            x[k] = b2f(xl[(size_t)s * 64 + c]);
        }

        int base = 0;
        while (true) {
            const int nxt = base + 8;
            const bool hn = nxt < n;
            float y[8];
#pragma unroll
            for (int k = 0; k < 8; k++) y[k] = 0.0f;
            if (hn) {                      // prefetch next oct BEFORE chains
#pragma unroll
                for (int k = 0; k < 8; k++) {
                    const int s = __shfl(lidx, (nxt + k) & 63, 64);
                    y[k] = b2f(xl[(size_t)s * 64 + c]);
                }
            }

            float u[8];
#pragma unroll
            for (int k = 0; k < 8; k++) {
                float v = x[k] + xrc;
                v = (v > 0.0f) ? v : 0.2f * v;
                u[k] = v * attc;
            }
#pragma unroll
            for (int off = 16; off > 0; off >>= 1) {  // per-32-lane (head) sum
#pragma unroll
                for (int k = 0; k < 8; k++)
                    u[k] += __shfl_xor(u[k], off, 64);
            }
#pragma unroll
            for (int k = 0; k < 8; k++) {
                const float e = (base + k < n) ? __expf(u[k]) : 0.0f;
                acc += e * x[k];
                den += e;
            }
            if (!hn) break;
#pragma unroll
            for (int k = 0; k < 8; k++) x[k] = y[k];
            base = nxt;
        }
        chunk = cend;
    }

    const float res = acc / den;
    if (MODE == 0) nw[dbase] = sbias[c] + res;
    else           nw[dbase] += res;
}

// ---------------------------------------------------------------------------
// LayerNorm(64) + affine + ReLU for BOTH node types in one launch.
// One wave per row; writes internal bf16 h.
// ---------------------------------------------------------------------------
__global__ __launch_bounds__(256) void ln_relu2(
    const float* __restrict__ nb_p, const float* __restrict__ nb_a,
    const void* __restrict__ g, int goff_p, int goff_a,
    const void* __restrict__ b, int boff_p, int boff_a,
    __hip_bfloat16* __restrict__ h_p, __hip_bfloat16* __restrict__ h_a,
    const int* __restrict__ flagp)
{
    int row = blockIdx.x * 4 + (threadIdx.x >> 6);
    const int c = threadIdx.x & 63;
    const int f32 = flagp[0];

    const float* nb; __hip_bfloat16* h; int goff, boff;
    if (row < NPAPER) {                     // NPAPER % 4 == 0: uniform block
        nb = nb_p; h = h_p; goff = goff_p; boff = boff_p;
    } else {
        row -= NPAPER;
        if (row >= NAUTHOR) return;
        nb = nb_a; h = h_a; goff = goff_a; boff = boff_a;
    }

    const float v = nb[(size_t)row * 64 + c];
    float s = v;
#pragma unroll
    for (int o = 32; o > 0; o >>= 1) s += __shfl_xor(s, o, 64);
    const float mu = s * (1.0f / 64.0f);
    const float dd = v - mu;
    float q = dd * dd;
#pragma unroll
    for (int o = 32; o > 0; o >>= 1) q += __shfl_xor(q, o, 64);
    const float var = q * (1.0f / 64.0f);
    float y = dd * rsqrtf(var + 1e-5f) * wireF(g, goff + c, f32)
            + wireF(b, boff + c, f32);
    y = (y < 0.0f) ? 0.0f : y;                  // NaN propagates
    h[(size_t)row * 64 + c] = __float2bfloat16(y);
}

// ---------------------------------------------------------------------------
extern "C" void kernel_launch(void* const* d_in, const int* in_sizes, int n_in,
                              void* d_out, int out_size, void* d_ws, size_t ws_size,
                              hipStream_t stream)
{
    const void* x_p   = d_in[0];
    const void* x_a   = d_in[1];
    const int* e_ws_s = (const int*)d_in[2];
    const int* e_ws_d = (const int*)d_in[3];
    const int* e_rv_s = (const int*)d_in[4];
    const int* e_rv_d = (const int*)d_in[5];
    const int* e_ci_s = (const int*)d_in[6];
    const int* e_ci_d = (const int*)d_in[7];
    const void* inW_p = d_in[8];
    const void* inW_a = d_in[9];
    const void* Wl    = d_in[10];
    const void* bl    = d_in[11];
    const void* Wr    = d_in[12];
    const void* br    = d_in[13];
    const void* att   = d_in[14];
    const void* gbias = d_in[15];
    const void* lng   = d_in[16];
    const void* lnb   = d_in[17];
    const void* oWp   = d_in[18];
    const void* obp   = d_in[19];
    const void* oWa   = d_in[20];
    const void* oba   = d_in[21];

    char* p = (char*)d_ws;
    auto carve = [&](size_t bytes) -> char* {
        char* r = p;
        p += (bytes + 255) & ~(size_t)255;
        return r;
    };
    int* flag = (int*)carve(256);
    __hip_bfloat16* h_p = (__hip_bfloat16*)carve((size_t)NPAPER  * 64 * 2);
    __hip_bfloat16* h_a = (__hip_bfloat16*)carve((size_t)NAUTHOR * 64 * 2);
    __hip_bfloat16* xl  = (__hip_bfloat16*)carve((size_t)NPAPER * 64 * 2);
    __hip_bfloat16* xr  = (__hip_bfloat16*)carve((size_t)NPAPER * 64 * 2);
    float* new_p = (float*)carve((size_t)NPAPER  * 64 * 4);
    float* new_a = (float*)carve((size_t)NAUTHOR * 64 * 4);
    int *csr_src[3], *row_ptr[3], *offs[3];
    for (int r = 0; r < 3; r++) {
        csr_src[r] = (int*)carve((size_t)NEDGE * 4);
        row_ptr[r] = (int*)carve(((size_t)NPAPER + 1) * 4);
        offs[r]    = (int*)carve((size_t)NPAPER * 4);
    }
    int* deg       = (int*)carve((size_t)3 * NPAPER * 4);   // [3][NPAPER]
    int* blocksums = (int*)carve(3 * 256 * 4);              // [3][256]

    detect_mode<<<dim3(1), dim3(64), 0, stream>>>((const unsigned*)lng, flag);

    // ---- CSR build, all 3 relations fused (reused by both layers) ----
    (void)hipMemsetAsync(deg, 0, (size_t)3 * NPAPER * 4, stream);
    hist3_k<<<dim3(3 * NB_E), dim3(256), 0, stream>>>(e_ws_d, e_rv_d, e_ci_d, deg);
    scan1_3k<<<dim3(NB1_P + NB1_A + NB1_P), dim3(256), 0, stream>>>(
        deg, row_ptr[0], row_ptr[1], row_ptr[2], blocksums);
    scan2_3k<<<dim3(3), dim3(256), 0, stream>>>(blocksums);
    scan3_3k<<<dim3(NB256_P + NB256_A + NB256_P), dim3(256), 0, stream>>>(
        row_ptr[0], row_ptr[1], row_ptr[2], offs[0], offs[1], offs[2], blocksums);
    scatter3_k<<<dim3(3 * NB_E), dim3(256), 0, stream>>>(
        e_ws_s, e_rv_s, e_ci_s, e_ws_d, e_rv_d, e_ci_d,
        offs[0], offs[1], offs[2], csr_src[0], csr_src[1], csr_src[2]);

    // ---- input projections (one launch, 2 jobs): h = x @ inW ----
    gemm256<128, 0, true><<<dim3(NB256_P + NB256_A), dim3(256), 0, stream>>>(
        x_p, inW_p, 0, nullptr, 0, h_p, NPAPER, 0, NB256_P,
        x_a, inW_a, 0, nullptr, 0, h_a, NAUTHOR, 0, flag);

    for (int l = 0; l < 2; l++) {
        const __hip_bfloat16* hs[3] = { h_a, h_p, h_p };   // source type
        const int             Ns[3] = { NAUTHOR, NPAPER, NPAPER };
        const int             Bs[3] = { NB256_A, NB256_P, NB256_P };
        const __hip_bfloat16* hd[3] = { h_p, h_a, h_p };   // dst type
        const int             Nd[3] = { NPAPER, NAUTHOR, NPAPER };
        const int             Bd[3] = { NB256_P, NB256_A, NB256_P };
        float* nb[3] = { new_p, new_a, new_p };

        for (int r = 0; r < 3; r++) {
            const int wo = (l * 3 + r) * 64 * 64;
            const int bo = (l * 3 + r) * 64;
            // xl and xr in ONE launch (2 jobs)
            gemm256<64, 0, false><<<dim3(Bs[r] + Bd[r]), dim3(256), 0, stream>>>(
                hs[r], Wl, wo, bl, bo, xl, Ns[r], 0, Bs[r],
                hd[r], Wr, wo, br, bo, xr, Nd[r], 0, flag);
            if (r == 0) {        // writes -> paper: WRITE, bias = g[l,0]+g[l,2]
                gat_dst<0><<<dim3((Nd[r] + 3) / 4), dim3(256), 0, stream>>>(
                    row_ptr[r], csr_src[r], xl, xr, att, bo,
                    gbias, (l * 3 + 0) * 64, gbias, (l * 3 + 2) * 64,
                    nb[r], Nd[r], flag);
            } else if (r == 1) { // rev -> author: WRITE, bias = g[l,1]
                gat_dst<0><<<dim3((Nd[r] + 3) / 4), dim3(256), 0, stream>>>(
                    row_ptr[r], csr_src[r], xl, xr, att, bo,
                    gbias, (l * 3 + 1) * 64, nullptr, 0,
                    nb[r], Nd[r], flag);
            } else {             // cites -> paper: ACCUMULATE
                gat_dst<1><<<dim3((Nd[r] + 3) / 4), dim3(256), 0, stream>>>(
                    row_ptr[r], csr_src[r], xl, xr, att, bo,
                    nullptr, 0, nullptr, 0,
                    nb[r], Nd[r], flag);
            }
        }

        ln_relu2<<<dim3((NPAPER + NAUTHOR) / 4), dim3(256), 0, stream>>>(
            new_p, new_a,
            lng, (l * 2 + 0) * 64, (l * 2 + 1) * 64,
            lnb, (l * 2 + 0) * 64, (l * 2 + 1) * 64,
            h_p, h_a, flag);
    }

    // ---- output projections (one launch, 2 jobs) into d_out ----
    gemm256<64, 2, false><<<dim3(NB256_P + NB256_A), dim3(256), 0, stream>>>(
        h_p, oWp, 0, obp, 0, d_out, NPAPER, 0, NB256_P,
        h_a, oWa, 0, oba, 0, d_out, NAUTHOR, NPAPER, flag);
}

// Round 3
// 1363.921 us; speedup vs baseline: 1.1594x; 1.1594x over previous
//
#include <hip/hip_runtime.h>
#include <hip/hip_bf16.h>

// ---------------------------------------------------------------------------
// HeteroGNN forward on MI355X — round 8: binned CSR build (no random atomics).
//   NP=200000, NA=100000, E=1e6 per relation (3 rels), DIN=128,
//   HID=64 (2 heads x 32), L=2 layers, DOUT=64.
// vs round 7:
//   * CSR build rebuilt: coarse bins of 1024 dst nodes. LDS histograms +
//     one global atomic per (block,bin) replace 6M random device atomics;
//     payload writes go to L2-hot bin segments (WRITE 212 MB -> ~12 MB).
//     Pipeline: csr_count -> csr_binscan -> csr_binscatter (packed
//     src|dst_lo<<18 per edge) -> csr_build (per-bin LDS counters, scan,
//     in-bin scatter; row_ptr written coalesced).
//   * gat_dst: uniform-branch guards skip k>=n prime/prefetch gathers
//     (no more duplicate-gather waste) and skip the 2nd reduce quad for
//     deg<=4 rows.
// Wire dtype auto-detected (fp32 vs bf16) from ln_scale (all-ones).
// ---------------------------------------------------------------------------

#define NPAPER  200000
#define NAUTHOR 100000
#define NEDGE   1000000

#define NB256_P 782       // ceil(NPAPER/256)
#define NB256_A 391       // ceil(NAUTHOR/256)

#define BIN_SHIFT 10
#define BIN_SIZE  1024
#define NBIN_P    196     // ceil(NPAPER/1024)
#define NBIN_A    98      // ceil(NAUTHOR/1024)
#define NBIN_TOT  (NBIN_P + NBIN_A + NBIN_P)   // 490
#define EPT       8
#define NBLK_BIN  489     // ceil(NEDGE/(256*EPT))

typedef __attribute__((ext_vector_type(8))) short short8;   // 8 x bf16 bits
typedef __attribute__((ext_vector_type(4))) float f32x4;

__device__ inline float b2f(__hip_bfloat16 v) { return __bfloat162float(v); }

__device__ inline short f2bs(float f) {        // fp32 -> bf16 bits (RNE)
    unsigned u = __float_as_uint(f);
    u += 0x7FFFu + ((u >> 16) & 1u);
    return (short)(u >> 16);
}

__device__ inline float wireF(const void* p, int i, int f32) {
    return f32 ? ((const float*)p)[i]
               : b2f(((const __hip_bfloat16*)p)[i]);
}

__device__ inline const int* sel3(int r, const int* a, const int* b, const int* c) {
    return r == 0 ? a : (r == 1 ? b : c);
}
__device__ inline int* sel3m(int r, int* a, int* b, int* c) {
    return r == 0 ? a : (r == 1 ? b : c);
}

__global__ void detect_mode(const unsigned* __restrict__ lns, int* __restrict__ flag) {
    if (threadIdx.x == 0 && blockIdx.x == 0)
        flag[0] = (lns[0] == 0x3F800000u) ? 1 : 0;   // 1 = fp32 wire
}

// ---------------------------------------------------------------------------
// GEMM: Y[row_off + 0..N, 0..64] = A[N,K] @ B[K,64] + bias, two jobs per
// launch (block ranges). 256-row tile per 256-thread block; each wave owns
// 64 rows (4 row-groups x 16), so K=64 gives 32 MFMAs per wave per stage.
// OUT_MODE: 0 = internal bf16, 2 = wire dtype (per flag).
// A_WIRE:   true = A is a wire tensor (dtype per flag), false = internal bf16.
// ---------------------------------------------------------------------------
template <int K, int OUT_MODE, bool A_WIRE>
__global__ __launch_bounds__(256) void gemm256(
    const void* __restrict__ A0v, const void* __restrict__ B0v, int b0_off,
    const void* __restrict__ bias0v, int bias0_off,
    void* __restrict__ Y0v, int N0, int row0_off, int nblk0,
    const void* __restrict__ A1v, const void* __restrict__ B1v, int b1_off,
    const void* __restrict__ bias1v, int bias1_off,
    void* __restrict__ Y1v, int N1, int row1_off,
    const int* __restrict__ flagp)
{
    const int f32 = flagp[0];
    int bid = blockIdx.x;
    const void* Av; const void* Bv; int b_off; const void* biasv; int bias_off;
    void* Yv; int N; int row_off;
    if (bid < nblk0) {
        Av = A0v; Bv = B0v; b_off = b0_off; biasv = bias0v; bias_off = bias0_off;
        Yv = Y0v; N = N0; row_off = row0_off;
    } else {
        bid -= nblk0;
        Av = A1v; Bv = B1v; b_off = b1_off; biasv = bias1v; bias_off = bias1_off;
        Yv = Y1v; N = N1; row_off = row1_off;
    }

    constexpr int SB = K + 8;
    __shared__ short Bs[64 * SB];
    __shared__ float sbias[64];

    const int tid = threadIdx.x;
    for (int idx = tid; idx < K * 64; idx += 256) {
        const int k = idx >> 6;                 // B is [K,64] row-major
        const int n = idx & 63;
        const short v = f32 ? f2bs(((const float*)Bv)[b_off + idx])
                            : ((const short*)Bv)[b_off + idx];
        Bs[n * SB + k] = v;
    }
    if (tid < 64)
        sbias[tid] = biasv ? wireF(biasv, bias_off + tid, f32) : 0.0f;
    __syncthreads();

    const int wave = tid >> 6;
    const int lane = tid & 63;
    const int l15  = lane & 15;
    const int quad = lane >> 4;
    const int row_base = bid * 256 + wave * 64;

    f32x4 acc[4][4] = {};                       // [row-group][col-group]

    int arow[4];
#pragma unroll
    for (int rg = 0; rg < 4; rg++) {
        int r = row_base + rg * 16 + l15;
        arow[rg] = (r < N) ? r : (N - 1);       // clamp; stores predicated
    }

#pragma unroll
    for (int kit = 0; kit < K / 32; kit++) {
        const int k0 = kit * 32 + quad * 8;
        short8 af[4];
#pragma unroll
        for (int rg = 0; rg < 4; rg++) {
            if (A_WIRE && f32) {
                const float* Ar = (const float*)Av + (size_t)arow[rg] * K + k0;
                const float4 a0 = *reinterpret_cast<const float4*>(Ar);
                const float4 a1 = *reinterpret_cast<const float4*>(Ar + 4);
                af[rg][0] = f2bs(a0.x); af[rg][1] = f2bs(a0.y);
                af[rg][2] = f2bs(a0.z); af[rg][3] = f2bs(a0.w);
                af[rg][4] = f2bs(a1.x); af[rg][5] = f2bs(a1.y);
                af[rg][6] = f2bs(a1.z); af[rg][7] = f2bs(a1.w);
            } else {
                af[rg] = *reinterpret_cast<const short8*>(
                    (const short*)Av + (size_t)arow[rg] * K + k0);
            }
        }
#pragma unroll
        for (int cg = 0; cg < 4; cg++) {
            const short8 bf = *reinterpret_cast<const short8*>(
                &Bs[(cg * 16 + l15) * SB + k0]);
#pragma unroll
            for (int rg = 0; rg < 4; rg++)
                acc[rg][cg] = __builtin_amdgcn_mfma_f32_16x16x32_bf16(
                    af[rg], bf, acc[rg][cg], 0, 0, 0);
        }
    }

#pragma unroll
    for (int rg = 0; rg < 4; rg++) {
#pragma unroll
        for (int cg = 0; cg < 4; cg++) {
            const int col = cg * 16 + l15;
            const float bv = sbias[col];
#pragma unroll
            for (int r = 0; r < 4; r++) {
                const int row = row_base + rg * 16 + quad * 4 + r;
                if (row < N) {
                    const float v = acc[rg][cg][r] + bv;
                    const size_t o = (size_t)(row + row_off) * 64 + col;
                    if (OUT_MODE == 0)
                        ((__hip_bfloat16*)Yv)[o] = __float2bfloat16(v);
                    else {
                        if (f32) ((float*)Yv)[o] = v;
                        else     ((__hip_bfloat16*)Yv)[o] = __float2bfloat16(v);
                    }
                }
            }
        }
    }
}

// ---------------------------------------------------------------------------
// Binned CSR build. Bins of 1024 dst nodes; all per-edge atomics are LDS.
// ---------------------------------------------------------------------------
// K1: per-block LDS bin histogram -> one global atomic per (block, bin).
__global__ __launch_bounds__(256) void csr_count(
    const int* __restrict__ d0, const int* __restrict__ d1,
    const int* __restrict__ d2, int* __restrict__ g_bincnt)
{
    int bid = blockIdx.x;
    const int rel = bid / NBLK_BIN;
    bid -= rel * NBLK_BIN;
    const int* dst = sel3(rel, d0, d1, d2);
    const int nbin = (rel == 1) ? NBIN_A : NBIN_P;
    const int boff = (rel == 0) ? 0 : ((rel == 1) ? NBIN_P : NBIN_P + NBIN_A);

    __shared__ int cnt[NBIN_P];
    for (int i = threadIdx.x; i < nbin; i += 256) cnt[i] = 0;
    __syncthreads();
    const int e0 = bid * (256 * EPT) + threadIdx.x;
#pragma unroll
    for (int i = 0; i < EPT; i++) {
        const int e = e0 + i * 256;
        if (e < NEDGE) atomicAdd(&cnt[dst[e] >> BIN_SHIFT], 1);
    }
    __syncthreads();
    for (int i = threadIdx.x; i < nbin; i += 256)
        if (cnt[i]) atomicAdd(&g_bincnt[boff + i], cnt[i]);
}

// K2: exclusive scan of the 490 bin counts (per relation); also writes the
// row_ptr[N] sentinels. g_binbase = CSR segment base per bin; g_binres =
// running reservation cursor for K3.
__global__ __launch_bounds__(256) void csr_binscan(
    const int* __restrict__ g_bincnt, int* __restrict__ g_binbase,
    int* __restrict__ g_binres,
    int* __restrict__ rp0, int* __restrict__ rp1, int* __restrict__ rp2)
{
    __shared__ int lds[NBIN_TOT];
    for (int i = threadIdx.x; i < NBIN_TOT; i += 256) lds[i] = g_bincnt[i];
    __syncthreads();
    if (threadIdx.x < 3) {
        const int rel  = threadIdx.x;
        const int nbin = (rel == 1) ? NBIN_A : NBIN_P;
        const int boff = (rel == 0) ? 0 : ((rel == 1) ? NBIN_P : NBIN_P + NBIN_A);
        int run = 0;
        for (int i = 0; i < nbin; i++) {
            const int cn = lds[boff + i];
            lds[boff + i] = run;
            run += cn;
        }
        int* rp = sel3m(rel, rp0, rp1, rp2);
        rp[(rel == 1) ? NAUTHOR : NPAPER] = NEDGE;
    }
    __syncthreads();
    for (int i = threadIdx.x; i < NBIN_TOT; i += 256) {
        const int v = lds[i];
        g_binbase[i] = v;
        g_binres[i]  = v;
    }
}

// K3: scatter edges into their bin segment (packed src | dst_lo<<18).
// LDS cursors assign within-block slots; one reservation atomic per
// (block, bin). Writes land in L2-hot bin segments.
__global__ __launch_bounds__(256) void csr_binscatter(
    const int* __restrict__ s0, const int* __restrict__ s1, const int* __restrict__ s2,
    const int* __restrict__ d0, const int* __restrict__ d1, const int* __restrict__ d2,
    int* __restrict__ g_binres, unsigned* __restrict__ binned)
{
    int bid = blockIdx.x;
    const int rel = bid / NBLK_BIN;
    bid -= rel * NBLK_BIN;
    const int* src = sel3(rel, s0, s1, s2);
    const int* dst = sel3(rel, d0, d1, d2);
    const int nbin = (rel == 1) ? NBIN_A : NBIN_P;
    const int boff = (rel == 0) ? 0 : ((rel == 1) ? NBIN_P : NBIN_P + NBIN_A);

    __shared__ int lcnt[NBIN_P];
    __shared__ int lbase[NBIN_P];
    for (int i = threadIdx.x; i < nbin; i += 256) lcnt[i] = 0;
    __syncthreads();

    const int e0 = bid * (256 * EPT) + threadIdx.x;
    int mybin[EPT], myslot[EPT];
    unsigned mypack[EPT];
#pragma unroll
    for (int i = 0; i < EPT; i++) {
        const int e = e0 + i * 256;
        if (e < NEDGE) {
            const int D = dst[e];
            const int b = D >> BIN_SHIFT;
            mybin[i]  = b;
            mypack[i] = (unsigned)src[e] | ((unsigned)(D & (BIN_SIZE - 1)) << 18);
            myslot[i] = atomicAdd(&lcnt[b], 1);
        } else mybin[i] = -1;
    }
    __syncthreads();
    for (int i = threadIdx.x; i < nbin; i += 256) {
        const int cn = lcnt[i];
        lbase[i] = cn ? atomicAdd(&g_binres[boff + i], cn) : 0;
    }
    __syncthreads();
    unsigned* bout = binned + (size_t)rel * NEDGE;
#pragma unroll
    for (int i = 0; i < EPT; i++)
        if (mybin[i] >= 0)
            bout[lbase[mybin[i]] + myslot[i]] = mypack[i];
}

// K4: one block per bin. LDS per-dst counters -> scan -> row_ptr (coalesced)
// -> in-bin scatter of csr_src (L2-hot region, LDS cursor atomics only).
__global__ __launch_bounds__(256) void csr_build(
    const unsigned* __restrict__ binned, const int* __restrict__ g_binbase,
    int* __restrict__ rp0, int* __restrict__ rp1, int* __restrict__ rp2,
    int* __restrict__ c0, int* __restrict__ c1, int* __restrict__ c2)
{
    int bid = blockIdx.x;
    int rel, nbin, boff, N;
    if (bid < NBIN_P)               { rel = 0; nbin = NBIN_P; boff = 0; N = NPAPER; }
    else if (bid < NBIN_P + NBIN_A) { rel = 1; bid -= NBIN_P; nbin = NBIN_A; boff = NBIN_P; N = NAUTHOR; }
    else { rel = 2; bid -= NBIN_P + NBIN_A; nbin = NBIN_P; boff = NBIN_P + NBIN_A; N = NPAPER; }

    const int base = g_binbase[boff + bid];
    const int next = (bid + 1 < nbin) ? g_binbase[boff + bid + 1] : NEDGE;
    const int cnt  = next - base;
    const unsigned* bin = binned + (size_t)rel * NEDGE + base;
    int* row_ptr = sel3m(rel, rp0, rp1, rp2);
    int* csr     = sel3m(rel, c0, c1, c2);

    __shared__ int off[BIN_SIZE];
    __shared__ int lds[256];
    for (int i = threadIdx.x; i < BIN_SIZE; i += 256) off[i] = 0;
    __syncthreads();
    for (int i = threadIdx.x; i < cnt; i += 256)
        atomicAdd(&off[bin[i] >> 18], 1);
    __syncthreads();

    const int t  = threadIdx.x;
    const int i4 = t * 4;
    const int v0 = off[i4], v1 = off[i4 + 1], v2 = off[i4 + 2], v3 = off[i4 + 3];
    const int tsum = v0 + v1 + v2 + v3;
    lds[t] = tsum;
    __syncthreads();
    for (int o = 1; o < 256; o <<= 1) {
        const int x = (t >= o) ? lds[t - o] : 0;
        __syncthreads();
        lds[t] += x;
        __syncthreads();
    }
    const int run = lds[t] - tsum;
    const int ex0 = run, ex1 = ex0 + v0, ex2 = ex1 + v1, ex3 = ex2 + v2;
    off[i4] = ex0; off[i4 + 1] = ex1; off[i4 + 2] = ex2; off[i4 + 3] = ex3;
    const int d0g = bid * BIN_SIZE + i4;
    if (d0g     < N) row_ptr[d0g]     = base + ex0;
    if (d0g + 1 < N) row_ptr[d0g + 1] = base + ex1;
    if (d0g + 2 < N) row_ptr[d0g + 2] = base + ex2;
    if (d0g + 3 < N) row_ptr[d0g + 3] = base + ex3;
    __syncthreads();

    for (int i = threadIdx.x; i < cnt; i += 256) {
        const unsigned pk = bin[i];
        const int slot = atomicAdd(&off[pk >> 18], 1);
        csr[base + slot] = (int)(pk & 0x3FFFFu);
    }
}

// ---------------------------------------------------------------------------
// GATv2 aggregation, wave per dst node, lane = channel (head = c>>5).
// 8 edges/iter, uniform-branch guards skip unused gathers and the 2nd
// reduce quad for short rows.
// MODE 0: nw[d] = bias + result (bias-only for deg-0 rows)
// MODE 1: nw[d] += result (skip deg-0)
// ---------------------------------------------------------------------------
template <int MODE>
__global__ __launch_bounds__(256) void gat_dst(
    const int* __restrict__ row_ptr, const int* __restrict__ csr_src,
    const __hip_bfloat16* __restrict__ xl, const __hip_bfloat16* __restrict__ xr,
    const void* __restrict__ att, int att_off,
    const void* __restrict__ b1, int off1,
    const void* __restrict__ b2, int off2,    // b2 may be null (MODE 0 only)
    float* __restrict__ nw, int Nd, const int* __restrict__ flagp)
{
    __shared__ float satt[64];
    __shared__ float sbias[64];
    if (threadIdx.x < 64) {
        const int f32 = flagp[0];
        satt[threadIdx.x] = wireF(att, att_off + threadIdx.x, f32);
        if (MODE == 0) {
            float bv = wireF(b1, off1 + threadIdx.x, f32);
            if (b2) bv += wireF(b2, off2 + threadIdx.x, f32);
            sbias[threadIdx.x] = bv;
        }
    }
    __syncthreads();

    const int d = blockIdx.x * 4 + (threadIdx.x >> 6);
    const int c = threadIdx.x & 63;
    if (d >= Nd) return;
    const int beg = row_ptr[d];
    const int end = row_ptr[d + 1];
    const size_t dbase = (size_t)d * 64 + c;

    if (beg == end) {                     // no incident edges
        if (MODE == 0) nw[dbase] = sbias[c];
        return;
    }

    const float xrc  = b2f(xr[dbase]);
    const float attc = satt[c];
    float acc = 0.0f, den = 0.0f;

    int chunk = beg;
    while (chunk < end) {
        const int cend = (chunk + 64 < end) ? (chunk + 64) : end;
        const int n    = cend - chunk;               // 1..64 edges this chunk
        // cooperative index load: lane c holds csr_src[chunk + c] (clamped)
        const int lidx = csr_src[chunk + ((c < n) ? c : 0)];

        // ---- 8-deep pipeline; uniform guards skip unused gathers ----
        float x[8];
#pragma unroll
        for (int k = 0; k < 8; k++) {
            if (k < n) {
                const int s = __shfl(lidx, k, 64);
                x[k] = b2f(xl[(size_t)s * 64 + c]);
            } else x[k] = 0.0f;
        }

        int base = 0;
        while (true) {
            const int nxt = base + 8;
            const bool hn = nxt < n;
            float y[8];
            if (hn) {                      // prefetch next oct BEFORE chains
#pragma unroll
                for (int k = 0; k < 8; k++) {
                    if (nxt + k < n) {
                        const int s = __shfl(lidx, (nxt + k) & 63, 64);
                        y[k] = b2f(xl[(size_t)s * 64 + c]);
                    } else y[k] = 0.0f;
                }
            }

            float u[8];
            // quad 0 (always: n - base >= 1)
#pragma unroll
            for (int k = 0; k < 4; k++) {
                float v = x[k] + xrc;
                v = (v > 0.0f) ? v : 0.2f * v;
                u[k] = v * attc;
            }
#pragma unroll
            for (int off = 16; off > 0; off >>= 1)
#pragma unroll
                for (int k = 0; k < 4; k++)
                    u[k] += __shfl_xor(u[k], off, 64);
#pragma unroll
            for (int k = 0; k < 4; k++) {
                const float e = (base + k < n) ? __expf(u[k]) : 0.0f;
                acc += e * x[k];
                den += e;
            }
            // quad 1 (skipped entirely for short rows — uniform branch)
            if (base + 4 < n) {
#pragma unroll
                for (int k = 4; k < 8; k++) {
                    float v = x[k] + xrc;
                    v = (v > 0.0f) ? v : 0.2f * v;
                    u[k] = v * attc;
                }
#pragma unroll
                for (int off = 16; off > 0; off >>= 1)
#pragma unroll
                    for (int k = 4; k < 8; k++)
                        u[k] += __shfl_xor(u[k], off, 64);
#pragma unroll
                for (int k = 4; k < 8; k++) {
                    const float e = (base + k < n) ? __expf(u[k]) : 0.0f;
                    acc += e * x[k];
                    den += e;
                }
            }
            if (!hn) break;
#pragma unroll
            for (int k = 0; k < 8; k++) x[k] = y[k];
            base = nxt;
        }
        chunk = cend;
    }

    const float res = acc / den;
    if (MODE == 0) nw[dbase] = sbias[c] + res;
    else           nw[dbase] += res;
}

// ---------------------------------------------------------------------------
// LayerNorm(64) + affine + ReLU for BOTH node types in one launch.
// One wave per row; writes internal bf16 h.
// ---------------------------------------------------------------------------
__global__ __launch_bounds__(256) void ln_relu2(
    const float* __restrict__ nb_p, const float* __restrict__ nb_a,
    const void* __restrict__ g, int goff_p, int goff_a,
    const void* __restrict__ b, int boff_p, int boff_a,
    __hip_bfloat16* __restrict__ h_p, __hip_bfloat16* __restrict__ h_a,
    const int* __restrict__ flagp)
{
    int row = blockIdx.x * 4 + (threadIdx.x >> 6);
    const int c = threadIdx.x & 63;
    const int f32 = flagp[0];

    const float* nb; __hip_bfloat16* h; int goff, boff;
    if (row < NPAPER) {                     // NPAPER % 4 == 0: uniform block
        nb = nb_p; h = h_p; goff = goff_p; boff = boff_p;
    } else {
        row -= NPAPER;
        if (row >= NAUTHOR) return;
        nb = nb_a; h = h_a; goff = goff_a; boff = boff_a;
    }

    const float v = nb[(size_t)row * 64 + c];
    float s = v;
#pragma unroll
    for (int o = 32; o > 0; o >>= 1) s += __shfl_xor(s, o, 64);
    const float mu = s * (1.0f / 64.0f);
    const float dd = v - mu;
    float q = dd * dd;
#pragma unroll
    for (int o = 32; o > 0; o >>= 1) q += __shfl_xor(q, o, 64);
    const float var = q * (1.0f / 64.0f);
    float y = dd * rsqrtf(var + 1e-5f) * wireF(g, goff + c, f32)
            + wireF(b, boff + c, f32);
    y = (y < 0.0f) ? 0.0f : y;                  // NaN propagates
    h[(size_t)row * 64 + c] = __float2bfloat16(y);
}

// ---------------------------------------------------------------------------
extern "C" void kernel_launch(void* const* d_in, const int* in_sizes, int n_in,
                              void* d_out, int out_size, void* d_ws, size_t ws_size,
                              hipStream_t stream)
{
    const void* x_p   = d_in[0];
    const void* x_a   = d_in[1];
    const int* e_ws_s = (const int*)d_in[2];
    const int* e_ws_d = (const int*)d_in[3];
    const int* e_rv_s = (const int*)d_in[4];
    const int* e_rv_d = (const int*)d_in[5];
    const int* e_ci_s = (const int*)d_in[6];
    const int* e_ci_d = (const int*)d_in[7];
    const void* inW_p = d_in[8];
    const void* inW_a = d_in[9];
    const void* Wl    = d_in[10];
    const void* bl    = d_in[11];
    const void* Wr    = d_in[12];
    const void* br    = d_in[13];
    const void* att   = d_in[14];
    const void* gbias = d_in[15];
    const void* lng   = d_in[16];
    const void* lnb   = d_in[17];
    const void* oWp   = d_in[18];
    const void* obp   = d_in[19];
    const void* oWa   = d_in[20];
    const void* oba   = d_in[21];

    char* p = (char*)d_ws;
    auto carve = [&](size_t bytes) -> char* {
        char* r = p;
        p += (bytes + 255) & ~(size_t)255;
        return r;
    };
    int* flag = (int*)carve(256);
    __hip_bfloat16* h_p = (__hip_bfloat16*)carve((size_t)NPAPER  * 64 * 2);
    __hip_bfloat16* h_a = (__hip_bfloat16*)carve((size_t)NAUTHOR * 64 * 2);
    __hip_bfloat16* xl  = (__hip_bfloat16*)carve((size_t)NPAPER * 64 * 2);
    __hip_bfloat16* xr  = (__hip_bfloat16*)carve((size_t)NPAPER * 64 * 2);
    float* new_p = (float*)carve((size_t)NPAPER  * 64 * 4);
    float* new_a = (float*)carve((size_t)NAUTHOR * 64 * 4);
    int *csr_src[3], *row_ptr[3];
    for (int r = 0; r < 3; r++) {
        csr_src[r] = (int*)carve((size_t)NEDGE * 4);
        row_ptr[r] = (int*)carve(((size_t)NPAPER + 1) * 4);
    }
    unsigned* binned = (unsigned*)carve((size_t)3 * NEDGE * 4);
    int* g_bincnt  = (int*)carve(NBIN_TOT * 4);
    int* g_binbase = (int*)carve(NBIN_TOT * 4);
    int* g_binres  = (int*)carve(NBIN_TOT * 4);

    detect_mode<<<dim3(1), dim3(64), 0, stream>>>((const unsigned*)lng, flag);

    // ---- binned CSR build, all 3 relations (reused by both layers) ----
    (void)hipMemsetAsync(g_bincnt, 0, NBIN_TOT * 4, stream);
    csr_count<<<dim3(3 * NBLK_BIN), dim3(256), 0, stream>>>(
        e_ws_d, e_rv_d, e_ci_d, g_bincnt);
    csr_binscan<<<dim3(1), dim3(256), 0, stream>>>(
        g_bincnt, g_binbase, g_binres, row_ptr[0], row_ptr[1], row_ptr[2]);
    csr_binscatter<<<dim3(3 * NBLK_BIN), dim3(256), 0, stream>>>(
        e_ws_s, e_rv_s, e_ci_s, e_ws_d, e_rv_d, e_ci_d, g_binres, binned);
    csr_build<<<dim3(NBIN_TOT), dim3(256), 0, stream>>>(
        binned, g_binbase, row_ptr[0], row_ptr[1], row_ptr[2],
        csr_src[0], csr_src[1], csr_src[2]);

    // ---- input projections (one launch, 2 jobs): h = x @ inW ----
    gemm256<128, 0, true><<<dim3(NB256_P + NB256_A), dim3(256), 0, stream>>>(
        x_p, inW_p, 0, nullptr, 0, h_p, NPAPER, 0, NB256_P,
        x_a, inW_a, 0, nullptr, 0, h_a, NAUTHOR, 0, flag);

    for (int l = 0; l < 2; l++) {
        const __hip_bfloat16* hs[3] = { h_a, h_p, h_p };   // source type
        const int             Ns[3] = { NAUTHOR, NPAPER, NPAPER };
        const int             Bs[3] = { NB256_A, NB256_P, NB256_P };
        const __hip_bfloat16* hd[3] = { h_p, h_a, h_p };   // dst type
        const int             Nd[3] = { NPAPER, NAUTHOR, NPAPER };
        const int             Bd[3] = { NB256_P, NB256_A, NB256_P };
        float* nb[3] = { new_p, new_a, new_p };

        for (int r = 0; r < 3; r++) {
            const int wo = (l * 3 + r) * 64 * 64;
            const int bo = (l * 3 + r) * 64;
            // xl and xr in ONE launch (2 jobs)
            gemm256<64, 0, false><<<dim3(Bs[r] + Bd[r]), dim3(256), 0, stream>>>(
                hs[r], Wl, wo, bl, bo, xl, Ns[r], 0, Bs[r],
                hd[r], Wr, wo, br, bo, xr, Nd[r], 0, flag);
            if (r == 0) {        // writes -> paper: WRITE, bias = g[l,0]+g[l,2]
                gat_dst<0><<<dim3((Nd[r] + 3) / 4), dim3(256), 0, stream>>>(
                    row_ptr[r], csr_src[r], xl, xr, att, bo,
                    gbias, (l * 3 + 0) * 64, gbias, (l * 3 + 2) * 64,
                    nb[r], Nd[r], flag);
            } else if (r == 1) { // rev -> author: WRITE, bias = g[l,1]
                gat_dst<0><<<dim3((Nd[r] + 3) / 4), dim3(256), 0, stream>>>(
                    row_ptr[r], csr_src[r], xl, xr, att, bo,
                    gbias, (l * 3 + 1) * 64, nullptr, 0,
                    nb[r], Nd[r], flag);
            } else {             // cites -> paper: ACCUMULATE
                gat_dst<1><<<dim3((Nd[r] + 3) / 4), dim3(256), 0, stream>>>(
                    row_ptr[r], csr_src[r], xl, xr, att, bo,
                    nullptr, 0, nullptr, 0,
                    nb[r], Nd[r], flag);
            }
        }

        ln_relu2<<<dim3((NPAPER + NAUTHOR) / 4), dim3(256), 0, stream>>>(
            new_p, new_a,
            lng, (l * 2 + 0) * 64, (l * 2 + 1) * 64,
            lnb, (l * 2 + 0) * 64, (l * 2 + 1) * 64,
            h_p, h_a, flag);
    }

    // ---- output projections (one launch, 2 jobs) into d_out ----
    gemm256<64, 2, false><<<dim3(NB256_P + NB256_A), dim3(256), 0, stream>>>(
        h_p, oWp, 0, obp, 0, d_out, NPAPER, 0, NB256_P,
        h_a, oWa, 0, oba, 0, d_out, NAUTHOR, NPAPER, flag);
}

// Round 4
// 1144.139 us; speedup vs baseline: 1.3821x; 1.1921x over previous
//
#include <hip/hip_runtime.h>
#include <hip/hip_bf16.h>

// ---------------------------------------------------------------------------
// HeteroGNN forward on MI355X — round 9: gat_dst DPP reduce + revert guards.
//   NP=200000, NA=100000, E=1e6 per relation (3 rels), DIN=128,
//   HID=64 (2 heads x 32), L=2 layers, DOUT=64.
// vs round 8:
//   * gat_dst back to the measured-good round-6 shape: 4-deep pipeline,
//     UNCONDITIONAL clamped gathers (no per-k branches -> loads cluster),
//     ternary-masked exp terms.
//   * per-head 32-lane reduce: 4x v_add DPP row_ror (16-lane rotate
//     butterfly) + ONE ds_swizzle xor-16 (0x401F) instead of 5 shuffle
//     ops -> LDS-pipe ops per edge 5 -> 1.
//   * binned CSR build kept from round 8 (big win: no random atomics).
// Wire dtype auto-detected (fp32 vs bf16) from ln_scale (all-ones).
// ---------------------------------------------------------------------------

#define NPAPER  200000
#define NAUTHOR 100000
#define NEDGE   1000000

#define NB256_P 782       // ceil(NPAPER/256)
#define NB256_A 391       // ceil(NAUTHOR/256)

#define BIN_SHIFT 10
#define BIN_SIZE  1024
#define NBIN_P    196     // ceil(NPAPER/1024)
#define NBIN_A    98      // ceil(NAUTHOR/1024)
#define NBIN_TOT  (NBIN_P + NBIN_A + NBIN_P)   // 490
#define EPT       8
#define NBLK_BIN  489     // ceil(NEDGE/(256*EPT))

typedef __attribute__((ext_vector_type(8))) short short8;   // 8 x bf16 bits
typedef __attribute__((ext_vector_type(4))) float f32x4;

__device__ inline float b2f(__hip_bfloat16 v) { return __bfloat162float(v); }

__device__ inline short f2bs(float f) {        // fp32 -> bf16 bits (RNE)
    unsigned u = __float_as_uint(f);
    u += 0x7FFFu + ((u >> 16) & 1u);
    return (short)(u >> 16);
}

__device__ inline float wireF(const void* p, int i, int f32) {
    return f32 ? ((const float*)p)[i]
               : b2f(((const __hip_bfloat16*)p)[i]);
}

__device__ inline const int* sel3(int r, const int* a, const int* b, const int* c) {
    return r == 0 ? a : (r == 1 ? b : c);
}
__device__ inline int* sel3m(int r, int* a, int* b, int* c) {
    return r == 0 ? a : (r == 1 ? b : c);
}

// ---- per-head (32-lane) sum: DPP rotate butterfly within 16-lane rows,
// ---- then one ds_swizzle xor-16 (operates within 32-lane groups).
template <int CTRL>
__device__ inline float dpp_add(float v) {
    const int r = __builtin_amdgcn_update_dpp(
        0, __float_as_int(v), CTRL, 0xF, 0xF, true);
    return v + __int_as_float(r);
}
__device__ inline float head_sum(float v) {
    v = dpp_add<0x128>(v);            // row_ror:8
    v = dpp_add<0x124>(v);            // row_ror:4
    v = dpp_add<0x122>(v);            // row_ror:2
    v = dpp_add<0x121>(v);            // row_ror:1  -> 16-lane row sums
    const int s = __builtin_amdgcn_ds_swizzle(__float_as_int(v), 0x401F);
    return v + __int_as_float(s);     // + partner row within the 32-half
}

__global__ void detect_mode(const unsigned* __restrict__ lns, int* __restrict__ flag) {
    if (threadIdx.x == 0 && blockIdx.x == 0)
        flag[0] = (lns[0] == 0x3F800000u) ? 1 : 0;   // 1 = fp32 wire
}

// ---------------------------------------------------------------------------
// GEMM: Y[row_off + 0..N, 0..64] = A[N,K] @ B[K,64] + bias, two jobs per
// launch (block ranges). 256-row tile per 256-thread block; each wave owns
// 64 rows (4 row-groups x 16), so K=64 gives 32 MFMAs per wave per stage.
// OUT_MODE: 0 = internal bf16, 2 = wire dtype (per flag).
// A_WIRE:   true = A is a wire tensor (dtype per flag), false = internal bf16.
// ---------------------------------------------------------------------------
template <int K, int OUT_MODE, bool A_WIRE>
__global__ __launch_bounds__(256) void gemm256(
    const void* __restrict__ A0v, const void* __restrict__ B0v, int b0_off,
    const void* __restrict__ bias0v, int bias0_off,
    void* __restrict__ Y0v, int N0, int row0_off, int nblk0,
    const void* __restrict__ A1v, const void* __restrict__ B1v, int b1_off,
    const void* __restrict__ bias1v, int bias1_off,
    void* __restrict__ Y1v, int N1, int row1_off,
    const int* __restrict__ flagp)
{
    const int f32 = flagp[0];
    int bid = blockIdx.x;
    const void* Av; const void* Bv; int b_off; const void* biasv; int bias_off;
    void* Yv; int N; int row_off;
    if (bid < nblk0) {
        Av = A0v; Bv = B0v; b_off = b0_off; biasv = bias0v; bias_off = bias0_off;
        Yv = Y0v; N = N0; row_off = row0_off;
    } else {
        bid -= nblk0;
        Av = A1v; Bv = B1v; b_off = b1_off; biasv = bias1v; bias_off = bias1_off;
        Yv = Y1v; N = N1; row_off = row1_off;
    }

    constexpr int SB = K + 8;
    __shared__ short Bs[64 * SB];
    __shared__ float sbias[64];

    const int tid = threadIdx.x;
    for (int idx = tid; idx < K * 64; idx += 256) {
        const int k = idx >> 6;                 // B is [K,64] row-major
        const int n = idx & 63;
        const short v = f32 ? f2bs(((const float*)Bv)[b_off + idx])
                            : ((const short*)Bv)[b_off + idx];
        Bs[n * SB + k] = v;
    }
    if (tid < 64)
        sbias[tid] = biasv ? wireF(biasv, bias_off + tid, f32) : 0.0f;
    __syncthreads();

    const int wave = tid >> 6;
    const int lane = tid & 63;
    const int l15  = lane & 15;
    const int quad = lane >> 4;
    const int row_base = bid * 256 + wave * 64;

    f32x4 acc[4][4] = {};                       // [row-group][col-group]

    int arow[4];
#pragma unroll
    for (int rg = 0; rg < 4; rg++) {
        int r = row_base + rg * 16 + l15;
        arow[rg] = (r < N) ? r : (N - 1);       // clamp; stores predicated
    }

#pragma unroll
    for (int kit = 0; kit < K / 32; kit++) {
        const int k0 = kit * 32 + quad * 8;
        short8 af[4];
#pragma unroll
        for (int rg = 0; rg < 4; rg++) {
            if (A_WIRE && f32) {
                const float* Ar = (const float*)Av + (size_t)arow[rg] * K + k0;
                const float4 a0 = *reinterpret_cast<const float4*>(Ar);
                const float4 a1 = *reinterpret_cast<const float4*>(Ar + 4);
                af[rg][0] = f2bs(a0.x); af[rg][1] = f2bs(a0.y);
                af[rg][2] = f2bs(a0.z); af[rg][3] = f2bs(a0.w);
                af[rg][4] = f2bs(a1.x); af[rg][5] = f2bs(a1.y);
                af[rg][6] = f2bs(a1.z); af[rg][7] = f2bs(a1.w);
            } else {
                af[rg] = *reinterpret_cast<const short8*>(
                    (const short*)Av + (size_t)arow[rg] * K + k0);
            }
        }
#pragma unroll
        for (int cg = 0; cg < 4; cg++) {
            const short8 bf = *reinterpret_cast<const short8*>(
                &Bs[(cg * 16 + l15) * SB + k0]);
#pragma unroll
            for (int rg = 0; rg < 4; rg++)
                acc[rg][cg] = __builtin_amdgcn_mfma_f32_16x16x32_bf16(
                    af[rg], bf, acc[rg][cg], 0, 0, 0);
        }
    }

#pragma unroll
    for (int rg = 0; rg < 4; rg++) {
#pragma unroll
        for (int cg = 0; cg < 4; cg++) {
            const int col = cg * 16 + l15;
            const float bv = sbias[col];
#pragma unroll
            for (int r = 0; r < 4; r++) {
                const int row = row_base + rg * 16 + quad * 4 + r;
                if (row < N) {
                    const float v = acc[rg][cg][r] + bv;
                    const size_t o = (size_t)(row + row_off) * 64 + col;
                    if (OUT_MODE == 0)
                        ((__hip_bfloat16*)Yv)[o] = __float2bfloat16(v);
                    else {
                        if (f32) ((float*)Yv)[o] = v;
                        else     ((__hip_bfloat16*)Yv)[o] = __float2bfloat16(v);
                    }
                }
            }
        }
    }
}

// ---------------------------------------------------------------------------
// Binned CSR build. Bins of 1024 dst nodes; all per-edge atomics are LDS.
// ---------------------------------------------------------------------------
__global__ __launch_bounds__(256) void csr_count(
    const int* __restrict__ d0, const int* __restrict__ d1,
    const int* __restrict__ d2, int* __restrict__ g_bincnt)
{
    int bid = blockIdx.x;
    const int rel = bid / NBLK_BIN;
    bid -= rel * NBLK_BIN;
    const int* dst = sel3(rel, d0, d1, d2);
    const int nbin = (rel == 1) ? NBIN_A : NBIN_P;
    const int boff = (rel == 0) ? 0 : ((rel == 1) ? NBIN_P : NBIN_P + NBIN_A);

    __shared__ int cnt[NBIN_P];
    for (int i = threadIdx.x; i < nbin; i += 256) cnt[i] = 0;
    __syncthreads();
    const int e0 = bid * (256 * EPT) + threadIdx.x;
#pragma unroll
    for (int i = 0; i < EPT; i++) {
        const int e = e0 + i * 256;
        if (e < NEDGE) atomicAdd(&cnt[dst[e] >> BIN_SHIFT], 1);
    }
    __syncthreads();
    for (int i = threadIdx.x; i < nbin; i += 256)
        if (cnt[i]) atomicAdd(&g_bincnt[boff + i], cnt[i]);
}

__global__ __launch_bounds__(256) void csr_binscan(
    const int* __restrict__ g_bincnt, int* __restrict__ g_binbase,
    int* __restrict__ g_binres,
    int* __restrict__ rp0, int* __restrict__ rp1, int* __restrict__ rp2)
{
    __shared__ int lds[NBIN_TOT];
    for (int i = threadIdx.x; i < NBIN_TOT; i += 256) lds[i] = g_bincnt[i];
    __syncthreads();
    if (threadIdx.x < 3) {
        const int rel  = threadIdx.x;
        const int nbin = (rel == 1) ? NBIN_A : NBIN_P;
        const int boff = (rel == 0) ? 0 : ((rel == 1) ? NBIN_P : NBIN_P + NBIN_A);
        int run = 0;
        for (int i = 0; i < nbin; i++) {
            const int cn = lds[boff + i];
            lds[boff + i] = run;
            run += cn;
        }
        int* rp = sel3m(rel, rp0, rp1, rp2);
        rp[(rel == 1) ? NAUTHOR : NPAPER] = NEDGE;
    }
    __syncthreads();
    for (int i = threadIdx.x; i < NBIN_TOT; i += 256) {
        const int v = lds[i];
        g_binbase[i] = v;
        g_binres[i]  = v;
    }
}

__global__ __launch_bounds__(256) void csr_binscatter(
    const int* __restrict__ s0, const int* __restrict__ s1, const int* __restrict__ s2,
    const int* __restrict__ d0, const int* __restrict__ d1, const int* __restrict__ d2,
    int* __restrict__ g_binres, unsigned* __restrict__ binned)
{
    int bid = blockIdx.x;
    const int rel = bid / NBLK_BIN;
    bid -= rel * NBLK_BIN;
    const int* src = sel3(rel, s0, s1, s2);
    const int* dst = sel3(rel, d0, d1, d2);
    const int nbin = (rel == 1) ? NBIN_A : NBIN_P;
    const int boff = (rel == 0) ? 0 : ((rel == 1) ? NBIN_P : NBIN_P + NBIN_A);

    __shared__ int lcnt[NBIN_P];
    __shared__ int lbase[NBIN_P];
    for (int i = threadIdx.x; i < nbin; i += 256) lcnt[i] = 0;
    __syncthreads();

    const int e0 = bid * (256 * EPT) + threadIdx.x;
    int mybin[EPT], myslot[EPT];
    unsigned mypack[EPT];
#pragma unroll
    for (int i = 0; i < EPT; i++) {
        const int e = e0 + i * 256;
        if (e < NEDGE) {
            const int D = dst[e];
            const int b = D >> BIN_SHIFT;
            mybin[i]  = b;
            mypack[i] = (unsigned)src[e] | ((unsigned)(D & (BIN_SIZE - 1)) << 18);
            myslot[i] = atomicAdd(&lcnt[b], 1);
        } else mybin[i] = -1;
    }
    __syncthreads();
    for (int i = threadIdx.x; i < nbin; i += 256) {
        const int cn = lcnt[i];
        lbase[i] = cn ? atomicAdd(&g_binres[boff + i], cn) : 0;
    }
    __syncthreads();
    unsigned* bout = binned + (size_t)rel * NEDGE;
#pragma unroll
    for (int i = 0; i < EPT; i++)
        if (mybin[i] >= 0)
            bout[lbase[mybin[i]] + myslot[i]] = mypack[i];
}

__global__ __launch_bounds__(256) void csr_build(
    const unsigned* __restrict__ binned, const int* __restrict__ g_binbase,
    int* __restrict__ rp0, int* __restrict__ rp1, int* __restrict__ rp2,
    int* __restrict__ c0, int* __restrict__ c1, int* __restrict__ c2)
{
    int bid = blockIdx.x;
    int rel, nbin, boff, N;
    if (bid < NBIN_P)               { rel = 0; nbin = NBIN_P; boff = 0; N = NPAPER; }
    else if (bid < NBIN_P + NBIN_A) { rel = 1; bid -= NBIN_P; nbin = NBIN_A; boff = NBIN_P; N = NAUTHOR; }
    else { rel = 2; bid -= NBIN_P + NBIN_A; nbin = NBIN_P; boff = NBIN_P + NBIN_A; N = NPAPER; }

    const int base = g_binbase[boff + bid];
    const int next = (bid + 1 < nbin) ? g_binbase[boff + bid + 1] : NEDGE;
    const int cnt  = next - base;
    const unsigned* bin = binned + (size_t)rel * NEDGE + base;
    int* row_ptr = sel3m(rel, rp0, rp1, rp2);
    int* csr     = sel3m(rel, c0, c1, c2);

    __shared__ int off[BIN_SIZE];
    __shared__ int lds[256];
    for (int i = threadIdx.x; i < BIN_SIZE; i += 256) off[i] = 0;
    __syncthreads();
    for (int i = threadIdx.x; i < cnt; i += 256)
        atomicAdd(&off[bin[i] >> 18], 1);
    __syncthreads();

    const int t  = threadIdx.x;
    const int i4 = t * 4;
    const int v0 = off[i4], v1 = off[i4 + 1], v2 = off[i4 + 2], v3 = off[i4 + 3];
    const int tsum = v0 + v1 + v2 + v3;
    lds[t] = tsum;
    __syncthreads();
    for (int o = 1; o < 256; o <<= 1) {
        const int x = (t >= o) ? lds[t - o] : 0;
        __syncthreads();
        lds[t] += x;
        __syncthreads();
    }
    const int run = lds[t] - tsum;
    const int ex0 = run, ex1 = ex0 + v0, ex2 = ex1 + v1, ex3 = ex2 + v2;
    off[i4] = ex0; off[i4 + 1] = ex1; off[i4 + 2] = ex2; off[i4 + 3] = ex3;
    const int d0g = bid * BIN_SIZE + i4;
    if (d0g     < N) row_ptr[d0g]     = base + ex0;
    if (d0g + 1 < N) row_ptr[d0g + 1] = base + ex1;
    if (d0g + 2 < N) row_ptr[d0g + 2] = base + ex2;
    if (d0g + 3 < N) row_ptr[d0g + 3] = base + ex3;
    __syncthreads();

    for (int i = threadIdx.x; i < cnt; i += 256) {
        const unsigned pk = bin[i];
        const int slot = atomicAdd(&off[pk >> 18], 1);
        csr[base + slot] = (int)(pk & 0x3FFFFu);
    }
}

// ---------------------------------------------------------------------------
// GATv2 aggregation, wave per dst node, lane = channel (head = c>>5).
// 4 edges/iter, unconditional clamped gathers (loads cluster), DPP reduce.
// MODE 0: nw[d] = bias + result (bias-only for deg-0 rows)
// MODE 1: nw[d] += result (skip deg-0)
// ---------------------------------------------------------------------------
template <int MODE>
__global__ __launch_bounds__(256) void gat_dst(
    const int* __restrict__ row_ptr, const int* __restrict__ csr_src,
    const __hip_bfloat16* __restrict__ xl, const __hip_bfloat16* __restrict__ xr,
    const void* __restrict__ att, int att_off,
    const void* __restrict__ b1, int off1,
    const void* __restrict__ b2, int off2,    // b2 may be null (MODE 0 only)
    float* __restrict__ nw, int Nd, const int* __restrict__ flagp)
{
    __shared__ float satt[64];
    __shared__ float sbias[64];
    if (threadIdx.x < 64) {
        const int f32 = flagp[0];
        satt[threadIdx.x] = wireF(att, att_off + threadIdx.x, f32);
        if (MODE == 0) {
            float bv = wireF(b1, off1 + threadIdx.x, f32);
            if (b2) bv += wireF(b2, off2 + threadIdx.x, f32);
            sbias[threadIdx.x] = bv;
        }
    }
    __syncthreads();

    const int d = blockIdx.x * 4 + (threadIdx.x >> 6);
    const int c = threadIdx.x & 63;
    if (d >= Nd) return;
    const int beg = row_ptr[d];
    const int end = row_ptr[d + 1];
    const size_t dbase = (size_t)d * 64 + c;

    if (beg == end) {                     // no incident edges
        if (MODE == 0) nw[dbase] = sbias[c];
        return;
    }

    const float xrc  = b2f(xr[dbase]);
    const float attc = satt[c];
    float acc = 0.0f, den = 0.0f;

    int chunk = beg;
    while (chunk < end) {
        const int cend = (chunk + 64 < end) ? (chunk + 64) : end;
        const int n    = cend - chunk;               // 1..64 edges this chunk
        // cooperative index load: lane c holds csr_src[chunk + c] (clamped)
        const int lidx = csr_src[chunk + ((c < n) ? c : 0)];

        // ---- 4-deep pipeline; gathers unconditional (clamped dup = L1 hit)
        float x0, x1, x2, x3;
        {
            const int s0 = __shfl(lidx, 0, 64);
            const int s1 = __shfl(lidx, 1, 64);
            const int s2 = __shfl(lidx, 2, 64);
            const int s3 = __shfl(lidx, 3, 64);
            x0 = b2f(xl[(size_t)s0 * 64 + c]);
            x1 = b2f(xl[(size_t)s1 * 64 + c]);
            x2 = b2f(xl[(size_t)s2 * 64 + c]);
            x3 = b2f(xl[(size_t)s3 * 64 + c]);
        }

        int base = 0;
        while (true) {
            const int nxt = base + 4;
            const bool hn = nxt < n;
            float y0 = 0.0f, y1 = 0.0f, y2 = 0.0f, y3 = 0.0f;
            if (hn) {                      // prefetch next quad BEFORE chains
                const int t0 = __shfl(lidx, (nxt + 0) & 63, 64);
                const int t1 = __shfl(lidx, (nxt + 1) & 63, 64);
                const int t2 = __shfl(lidx, (nxt + 2) & 63, 64);
                const int t3 = __shfl(lidx, (nxt + 3) & 63, 64);
                y0 = b2f(xl[(size_t)t0 * 64 + c]);
                y1 = b2f(xl[(size_t)t1 * 64 + c]);
                y2 = b2f(xl[(size_t)t2 * 64 + c]);
                y3 = b2f(xl[(size_t)t3 * 64 + c]);
            }

            float u0 = x0 + xrc; u0 = (u0 > 0.0f) ? u0 : 0.2f * u0; u0 *= attc;
            float u1 = x1 + xrc; u1 = (u1 > 0.0f) ? u1 : 0.2f * u1; u1 *= attc;
            float u2 = x2 + xrc; u2 = (u2 > 0.0f) ? u2 : 0.2f * u2; u2 *= attc;
            float u3 = x3 + xrc; u3 = (u3 > 0.0f) ? u3 : 0.2f * u3; u3 *= attc;

            u0 = head_sum(u0);            // DPP butterfly + 1 ds_swizzle
            u1 = head_sum(u1);
            u2 = head_sum(u2);
            u3 = head_sum(u3);

            const float e0 = (base + 0 < n) ? __expf(u0) : 0.0f;
            const float e1 = (base + 1 < n) ? __expf(u1) : 0.0f;
            const float e2 = (base + 2 < n) ? __expf(u2) : 0.0f;
            const float e3 = (base + 3 < n) ? __expf(u3) : 0.0f;
            acc += e0 * x0 + e1 * x1;
            acc += e2 * x2 + e3 * x3;
            den += (e0 + e1) + (e2 + e3);
            if (!hn) break;
            x0 = y0; x1 = y1; x2 = y2; x3 = y3;
            base = nxt;
        }
        chunk = cend;
    }

    const float res = acc / den;
    if (MODE == 0) nw[dbase] = sbias[c] + res;
    else           nw[dbase] += res;
}

// ---------------------------------------------------------------------------
// LayerNorm(64) + affine + ReLU for BOTH node types in one launch.
// One wave per row; writes internal bf16 h.
// ---------------------------------------------------------------------------
__global__ __launch_bounds__(256) void ln_relu2(
    const float* __restrict__ nb_p, const float* __restrict__ nb_a,
    const void* __restrict__ g, int goff_p, int goff_a,
    const void* __restrict__ b, int boff_p, int boff_a,
    __hip_bfloat16* __restrict__ h_p, __hip_bfloat16* __restrict__ h_a,
    const int* __restrict__ flagp)
{
    int row = blockIdx.x * 4 + (threadIdx.x >> 6);
    const int c = threadIdx.x & 63;
    const int f32 = flagp[0];

    const float* nb; __hip_bfloat16* h; int goff, boff;
    if (row < NPAPER) {                     // NPAPER % 4 == 0: uniform block
        nb = nb_p; h = h_p; goff = goff_p; boff = boff_p;
    } else {
        row -= NPAPER;
        if (row >= NAUTHOR) return;
        nb = nb_a; h = h_a; goff = goff_a; boff = boff_a;
    }

    const float v = nb[(size_t)row * 64 + c];
    float s = v;
#pragma unroll
    for (int o = 32; o > 0; o >>= 1) s += __shfl_xor(s, o, 64);
    const float mu = s * (1.0f / 64.0f);
    const float dd = v - mu;
    float q = dd * dd;
#pragma unroll
    for (int o = 32; o > 0; o >>= 1) q += __shfl_xor(q, o, 64);
    const float var = q * (1.0f / 64.0f);
    float y = dd * rsqrtf(var + 1e-5f) * wireF(g, goff + c, f32)
            + wireF(b, boff + c, f32);
    y = (y < 0.0f) ? 0.0f : y;                  // NaN propagates
    h[(size_t)row * 64 + c] = __float2bfloat16(y);
}

// ---------------------------------------------------------------------------
extern "C" void kernel_launch(void* const* d_in, const int* in_sizes, int n_in,
                              void* d_out, int out_size, void* d_ws, size_t ws_size,
                              hipStream_t stream)
{
    const void* x_p   = d_in[0];
    const void* x_a   = d_in[1];
    const int* e_ws_s = (const int*)d_in[2];
    const int* e_ws_d = (const int*)d_in[3];
    const int* e_rv_s = (const int*)d_in[4];
    const int* e_rv_d = (const int*)d_in[5];
    const int* e_ci_s = (const int*)d_in[6];
    const int* e_ci_d = (const int*)d_in[7];
    const void* inW_p = d_in[8];
    const void* inW_a = d_in[9];
    const void* Wl    = d_in[10];
    const void* bl    = d_in[11];
    const void* Wr    = d_in[12];
    const void* br    = d_in[13];
    const void* att   = d_in[14];
    const void* gbias = d_in[15];
    const void* lng   = d_in[16];
    const void* lnb   = d_in[17];
    const void* oWp   = d_in[18];
    const void* obp   = d_in[19];
    const void* oWa   = d_in[20];
    const void* oba   = d_in[21];

    char* p = (char*)d_ws;
    auto carve = [&](size_t bytes) -> char* {
        char* r = p;
        p += (bytes + 255) & ~(size_t)255;
        return r;
    };
    int* flag = (int*)carve(256);
    __hip_bfloat16* h_p = (__hip_bfloat16*)carve((size_t)NPAPER  * 64 * 2);
    __hip_bfloat16* h_a = (__hip_bfloat16*)carve((size_t)NAUTHOR * 64 * 2);
    __hip_bfloat16* xl  = (__hip_bfloat16*)carve((size_t)NPAPER * 64 * 2);
    __hip_bfloat16* xr  = (__hip_bfloat16*)carve((size_t)NPAPER * 64 * 2);
    float* new_p = (float*)carve((size_t)NPAPER  * 64 * 4);
    float* new_a = (float*)carve((size_t)NAUTHOR * 64 * 4);
    int *csr_src[3], *row_ptr[3];
    for (int r = 0; r < 3; r++) {
        csr_src[r] = (int*)carve((size_t)NEDGE * 4);
        row_ptr[r] = (int*)carve(((size_t)NPAPER + 1) * 4);
    }
    unsigned* binned = (unsigned*)carve((size_t)3 * NEDGE * 4);
    int* g_bincnt  = (int*)carve(NBIN_TOT * 4);
    int* g_binbase = (int*)carve(NBIN_TOT * 4);
    int* g_binres  = (int*)carve(NBIN_TOT * 4);

    detect_mode<<<dim3(1), dim3(64), 0, stream>>>((const unsigned*)lng, flag);

    // ---- binned CSR build, all 3 relations (reused by both layers) ----
    (void)hipMemsetAsync(g_bincnt, 0, NBIN_TOT * 4, stream);
    csr_count<<<dim3(3 * NBLK_BIN), dim3(256), 0, stream>>>(
        e_ws_d, e_rv_d, e_ci_d, g_bincnt);
    csr_binscan<<<dim3(1), dim3(256), 0, stream>>>(
        g_bincnt, g_binbase, g_binres, row_ptr[0], row_ptr[1], row_ptr[2]);
    csr_binscatter<<<dim3(3 * NBLK_BIN), dim3(256), 0, stream>>>(
        e_ws_s, e_rv_s, e_ci_s, e_ws_d, e_rv_d, e_ci_d, g_binres, binned);
    csr_build<<<dim3(NBIN_TOT), dim3(256), 0, stream>>>(
        binned, g_binbase, row_ptr[0], row_ptr[1], row_ptr[2],
        csr_src[0], csr_src[1], csr_src[2]);

    // ---- input projections (one launch, 2 jobs): h = x @ inW ----
    gemm256<128, 0, true><<<dim3(NB256_P + NB256_A), dim3(256), 0, stream>>>(
        x_p, inW_p, 0, nullptr, 0, h_p, NPAPER, 0, NB256_P,
        x_a, inW_a, 0, nullptr, 0, h_a, NAUTHOR, 0, flag);

    for (int l = 0; l < 2; l++) {
        const __hip_bfloat16* hs[3] = { h_a, h_p, h_p };   // source type
        const int             Ns[3] = { NAUTHOR, NPAPER, NPAPER };
        const int             Bs[3] = { NB256_A, NB256_P, NB256_P };
        const __hip_bfloat16* hd[3] = { h_p, h_a, h_p };   // dst type
        const int             Nd[3] = { NPAPER, NAUTHOR, NPAPER };
        const int             Bd[3] = { NB256_P, NB256_A, NB256_P };
        float* nb[3] = { new_p, new_a, new_p };

        for (int r = 0; r < 3; r++) {
            const int wo = (l * 3 + r) * 64 * 64;
            const int bo = (l * 3 + r) * 64;
            // xl and xr in ONE launch (2 jobs)
            gemm256<64, 0, false><<<dim3(Bs[r] + Bd[r]), dim3(256), 0, stream>>>(
                hs[r], Wl, wo, bl, bo, xl, Ns[r], 0, Bs[r],
                hd[r], Wr, wo, br, bo, xr, Nd[r], 0, flag);
            if (r == 0) {        // writes -> paper: WRITE, bias = g[l,0]+g[l,2]
                gat_dst<0><<<dim3((Nd[r] + 3) / 4), dim3(256), 0, stream>>>(
                    row_ptr[r], csr_src[r], xl, xr, att, bo,
                    gbias, (l * 3 + 0) * 64, gbias, (l * 3 + 2) * 64,
                    nb[r], Nd[r], flag);
            } else if (r == 1) { // rev -> author: WRITE, bias = g[l,1]
                gat_dst<0><<<dim3((Nd[r] + 3) / 4), dim3(256), 0, stream>>>(
                    row_ptr[r], csr_src[r], xl, xr, att, bo,
                    gbias, (l * 3 + 1) * 64, nullptr, 0,
                    nb[r], Nd[r], flag);
            } else {             // cites -> paper: ACCUMULATE
                gat_dst<1><<<dim3((Nd[r] + 3) / 4), dim3(256), 0, stream>>>(
                    row_ptr[r], csr_src[r], xl, xr, att, bo,
                    nullptr, 0, nullptr, 0,
                    nb[r], Nd[r], flag);
            }
        }

        ln_relu2<<<dim3((NPAPER + NAUTHOR) / 4), dim3(256), 0, stream>>>(
            new_p, new_a,
            lng, (l * 2 + 0) * 64, (l * 2 + 1) * 64,
            lnb, (l * 2 + 0) * 64, (l * 2 + 1) * 64,
            h_p, h_a, flag);
    }

    // ---- output projections (one launch, 2 jobs) into d_out ----
    gemm256<64, 2, false><<<dim3(NB256_P + NB256_A), dim3(256), 0, stream>>>(
        h_p, oWp, 0, obp, 0, d_out, NPAPER, 0, NB256_P,
        h_a, oWa, 0, oba, 0, d_out, NAUTHOR, NPAPER, flag);
}

// Round 5
// 1080.697 us; speedup vs baseline: 1.4632x; 1.0587x over previous
//
#include <hip/hip_runtime.h>
#include <hip/hip_bf16.h>

// ---------------------------------------------------------------------------
// HeteroGNN forward on MI355X — round 10: packed gat_dst (2 ch/lane, 2 edges/wave).
//   NP=200000, NA=100000, E=1e6 per relation (3 rels), DIN=128,
//   HID=64 (2 heads x 32), L=2 layers, DOUT=64.
// vs round 9:
//   * gat_dst repacked: lane = (half, channel-pair). Each 4B gather fetches
//     2 bf16 channels; halves process 2 edges concurrently -> one wave inst
//     per {gather, exp, fma} covers TWO edges. Head (32 ch) = 16 lanes ->
//     reduce is in-lane pair-add + 4 DPP row_ror, NO ds_swizzle.
//     ~23 -> ~12 wave-inst per edge in a VALU-issue-bound kernel.
//   * epilogue: 3x shfl_xor(32) cross-half combine, float2 store (half 0).
//   * binned CSR + fused GEMM/ln launches kept from rounds 8-9.
// Wire dtype auto-detected (fp32 vs bf16) from ln_scale (all-ones).
// ---------------------------------------------------------------------------

#define NPAPER  200000
#define NAUTHOR 100000
#define NEDGE   1000000

#define NB256_P 782       // ceil(NPAPER/256)
#define NB256_A 391       // ceil(NAUTHOR/256)

#define BIN_SHIFT 10
#define BIN_SIZE  1024
#define NBIN_P    196     // ceil(NPAPER/1024)
#define NBIN_A    98      // ceil(NAUTHOR/1024)
#define NBIN_TOT  (NBIN_P + NBIN_A + NBIN_P)   // 490
#define EPT       8
#define NBLK_BIN  489     // ceil(NEDGE/(256*EPT))

typedef __attribute__((ext_vector_type(8))) short short8;   // 8 x bf16 bits
typedef __attribute__((ext_vector_type(4))) float f32x4;

__device__ inline float b2f(__hip_bfloat16 v) { return __bfloat162float(v); }

__device__ inline short f2bs(float f) {        // fp32 -> bf16 bits (RNE)
    unsigned u = __float_as_uint(f);
    u += 0x7FFFu + ((u >> 16) & 1u);
    return (short)(u >> 16);
}

__device__ inline float wireF(const void* p, int i, int f32) {
    return f32 ? ((const float*)p)[i]
               : b2f(((const __hip_bfloat16*)p)[i]);
}

__device__ inline const int* sel3(int r, const int* a, const int* b, const int* c) {
    return r == 0 ? a : (r == 1 ? b : c);
}
__device__ inline int* sel3m(int r, int* a, int* b, int* c) {
    return r == 0 ? a : (r == 1 ? b : c);
}

// unpack 2 bf16 from a dword
__device__ inline float bf_lo(unsigned u) { return __uint_as_float(u << 16); }
__device__ inline float bf_hi(unsigned u) { return __uint_as_float(u & 0xFFFF0000u); }

// ---- 16-lane-row sum via DPP rotate butterfly (heads align to rows) ----
template <int CTRL>
__device__ inline float dpp_add(float v) {
    const int r = __builtin_amdgcn_update_dpp(
        0, __float_as_int(v), CTRL, 0xF, 0xF, true);
    return v + __int_as_float(r);
}
__device__ inline float hs16(float v) {
    v = dpp_add<0x128>(v);            // row_ror:8
    v = dpp_add<0x124>(v);            // row_ror:4
    v = dpp_add<0x122>(v);            // row_ror:2
    v = dpp_add<0x121>(v);            // row_ror:1  -> 16-lane row sums
    return v;
}

__global__ void detect_mode(const unsigned* __restrict__ lns, int* __restrict__ flag) {
    if (threadIdx.x == 0 && blockIdx.x == 0)
        flag[0] = (lns[0] == 0x3F800000u) ? 1 : 0;   // 1 = fp32 wire
}

// ---------------------------------------------------------------------------
// GEMM: Y[row_off + 0..N, 0..64] = A[N,K] @ B[K,64] + bias, two jobs per
// launch (block ranges). 256-row tile per 256-thread block.
// ---------------------------------------------------------------------------
template <int K, int OUT_MODE, bool A_WIRE>
__global__ __launch_bounds__(256) void gemm256(
    const void* __restrict__ A0v, const void* __restrict__ B0v, int b0_off,
    const void* __restrict__ bias0v, int bias0_off,
    void* __restrict__ Y0v, int N0, int row0_off, int nblk0,
    const void* __restrict__ A1v, const void* __restrict__ B1v, int b1_off,
    const void* __restrict__ bias1v, int bias1_off,
    void* __restrict__ Y1v, int N1, int row1_off,
    const int* __restrict__ flagp)
{
    const int f32 = flagp[0];
    int bid = blockIdx.x;
    const void* Av; const void* Bv; int b_off; const void* biasv; int bias_off;
    void* Yv; int N; int row_off;
    if (bid < nblk0) {
        Av = A0v; Bv = B0v; b_off = b0_off; biasv = bias0v; bias_off = bias0_off;
        Yv = Y0v; N = N0; row_off = row0_off;
    } else {
        bid -= nblk0;
        Av = A1v; Bv = B1v; b_off = b1_off; biasv = bias1v; bias_off = bias1_off;
        Yv = Y1v; N = N1; row_off = row1_off;
    }

    constexpr int SB = K + 8;
    __shared__ short Bs[64 * SB];
    __shared__ float sbias[64];

    const int tid = threadIdx.x;
    for (int idx = tid; idx < K * 64; idx += 256) {
        const int k = idx >> 6;                 // B is [K,64] row-major
        const int n = idx & 63;
        const short v = f32 ? f2bs(((const float*)Bv)[b_off + idx])
                            : ((const short*)Bv)[b_off + idx];
        Bs[n * SB + k] = v;
    }
    if (tid < 64)
        sbias[tid] = biasv ? wireF(biasv, bias_off + tid, f32) : 0.0f;
    __syncthreads();

    const int wave = tid >> 6;
    const int lane = tid & 63;
    const int l15  = lane & 15;
    const int quad = lane >> 4;
    const int row_base = bid * 256 + wave * 64;

    f32x4 acc[4][4] = {};                       // [row-group][col-group]

    int arow[4];
#pragma unroll
    for (int rg = 0; rg < 4; rg++) {
        int r = row_base + rg * 16 + l15;
        arow[rg] = (r < N) ? r : (N - 1);       // clamp; stores predicated
    }

#pragma unroll
    for (int kit = 0; kit < K / 32; kit++) {
        const int k0 = kit * 32 + quad * 8;
        short8 af[4];
#pragma unroll
        for (int rg = 0; rg < 4; rg++) {
            if (A_WIRE && f32) {
                const float* Ar = (const float*)Av + (size_t)arow[rg] * K + k0;
                const float4 a0 = *reinterpret_cast<const float4*>(Ar);
                const float4 a1 = *reinterpret_cast<const float4*>(Ar + 4);
                af[rg][0] = f2bs(a0.x); af[rg][1] = f2bs(a0.y);
                af[rg][2] = f2bs(a0.z); af[rg][3] = f2bs(a0.w);
                af[rg][4] = f2bs(a1.x); af[rg][5] = f2bs(a1.y);
                af[rg][6] = f2bs(a1.z); af[rg][7] = f2bs(a1.w);
            } else {
                af[rg] = *reinterpret_cast<const short8*>(
                    (const short*)Av + (size_t)arow[rg] * K + k0);
            }
        }
#pragma unroll
        for (int cg = 0; cg < 4; cg++) {
            const short8 bf = *reinterpret_cast<const short8*>(
                &Bs[(cg * 16 + l15) * SB + k0]);
#pragma unroll
            for (int rg = 0; rg < 4; rg++)
                acc[rg][cg] = __builtin_amdgcn_mfma_f32_16x16x32_bf16(
                    af[rg], bf, acc[rg][cg], 0, 0, 0);
        }
    }

#pragma unroll
    for (int rg = 0; rg < 4; rg++) {
#pragma unroll
        for (int cg = 0; cg < 4; cg++) {
            const int col = cg * 16 + l15;
            const float bv = sbias[col];
#pragma unroll
            for (int r = 0; r < 4; r++) {
                const int row = row_base + rg * 16 + quad * 4 + r;
                if (row < N) {
                    const float v = acc[rg][cg][r] + bv;
                    const size_t o = (size_t)(row + row_off) * 64 + col;
                    if (OUT_MODE == 0)
                        ((__hip_bfloat16*)Yv)[o] = __float2bfloat16(v);
                    else {
                        if (f32) ((float*)Yv)[o] = v;
                        else     ((__hip_bfloat16*)Yv)[o] = __float2bfloat16(v);
                    }
                }
            }
        }
    }
}

// ---------------------------------------------------------------------------
// Binned CSR build. Bins of 1024 dst nodes; all per-edge atomics are LDS.
// ---------------------------------------------------------------------------
__global__ __launch_bounds__(256) void csr_count(
    const int* __restrict__ d0, const int* __restrict__ d1,
    const int* __restrict__ d2, int* __restrict__ g_bincnt)
{
    int bid = blockIdx.x;
    const int rel = bid / NBLK_BIN;
    bid -= rel * NBLK_BIN;
    const int* dst = sel3(rel, d0, d1, d2);
    const int nbin = (rel == 1) ? NBIN_A : NBIN_P;
    const int boff = (rel == 0) ? 0 : ((rel == 1) ? NBIN_P : NBIN_P + NBIN_A);

    __shared__ int cnt[NBIN_P];
    for (int i = threadIdx.x; i < nbin; i += 256) cnt[i] = 0;
    __syncthreads();
    const int e0 = bid * (256 * EPT) + threadIdx.x;
#pragma unroll
    for (int i = 0; i < EPT; i++) {
        const int e = e0 + i * 256;
        if (e < NEDGE) atomicAdd(&cnt[dst[e] >> BIN_SHIFT], 1);
    }
    __syncthreads();
    for (int i = threadIdx.x; i < nbin; i += 256)
        if (cnt[i]) atomicAdd(&g_bincnt[boff + i], cnt[i]);
}

__global__ __launch_bounds__(256) void csr_binscan(
    const int* __restrict__ g_bincnt, int* __restrict__ g_binbase,
    int* __restrict__ g_binres,
    int* __restrict__ rp0, int* __restrict__ rp1, int* __restrict__ rp2)
{
    __shared__ int lds[NBIN_TOT];
    for (int i = threadIdx.x; i < NBIN_TOT; i += 256) lds[i] = g_bincnt[i];
    __syncthreads();
    if (threadIdx.x < 3) {
        const int rel  = threadIdx.x;
        const int nbin = (rel == 1) ? NBIN_A : NBIN_P;
        const int boff = (rel == 0) ? 0 : ((rel == 1) ? NBIN_P : NBIN_P + NBIN_A);
        int run = 0;
        for (int i = 0; i < nbin; i++) {
            const int cn = lds[boff + i];
            lds[boff + i] = run;
            run += cn;
        }
        int* rp = sel3m(rel, rp0, rp1, rp2);
        rp[(rel == 1) ? NAUTHOR : NPAPER] = NEDGE;
    }
    __syncthreads();
    for (int i = threadIdx.x; i < NBIN_TOT; i += 256) {
        const int v = lds[i];
        g_binbase[i] = v;
        g_binres[i]  = v;
    }
}

__global__ __launch_bounds__(256) void csr_binscatter(
    const int* __restrict__ s0, const int* __restrict__ s1, const int* __restrict__ s2,
    const int* __restrict__ d0, const int* __restrict__ d1, const int* __restrict__ d2,
    int* __restrict__ g_binres, unsigned* __restrict__ binned)
{
    int bid = blockIdx.x;
    const int rel = bid / NBLK_BIN;
    bid -= rel * NBLK_BIN;
    const int* src = sel3(rel, s0, s1, s2);
    const int* dst = sel3(rel, d0, d1, d2);
    const int nbin = (rel == 1) ? NBIN_A : NBIN_P;
    const int boff = (rel == 0) ? 0 : ((rel == 1) ? NBIN_P : NBIN_P + NBIN_A);

    __shared__ int lcnt[NBIN_P];
    __shared__ int lbase[NBIN_P];
    for (int i = threadIdx.x; i < nbin; i += 256) lcnt[i] = 0;
    __syncthreads();

    const int e0 = bid * (256 * EPT) + threadIdx.x;
    int mybin[EPT], myslot[EPT];
    unsigned mypack[EPT];
#pragma unroll
    for (int i = 0; i < EPT; i++) {
        const int e = e0 + i * 256;
        if (e < NEDGE) {
            const int D = dst[e];
            const int b = D >> BIN_SHIFT;
            mybin[i]  = b;
            mypack[i] = (unsigned)src[e] | ((unsigned)(D & (BIN_SIZE - 1)) << 18);
            myslot[i] = atomicAdd(&lcnt[b], 1);
        } else mybin[i] = -1;
    }
    __syncthreads();
    for (int i = threadIdx.x; i < nbin; i += 256) {
        const int cn = lcnt[i];
        lbase[i] = cn ? atomicAdd(&g_binres[boff + i], cn) : 0;
    }
    __syncthreads();
    unsigned* bout = binned + (size_t)rel * NEDGE;
#pragma unroll
    for (int i = 0; i < EPT; i++)
        if (mybin[i] >= 0)
            bout[lbase[mybin[i]] + myslot[i]] = mypack[i];
}

__global__ __launch_bounds__(256) void csr_build(
    const unsigned* __restrict__ binned, const int* __restrict__ g_binbase,
    int* __restrict__ rp0, int* __restrict__ rp1, int* __restrict__ rp2,
    int* __restrict__ c0, int* __restrict__ c1, int* __restrict__ c2)
{
    int bid = blockIdx.x;
    int rel, nbin, boff, N;
    if (bid < NBIN_P)               { rel = 0; nbin = NBIN_P; boff = 0; N = NPAPER; }
    else if (bid < NBIN_P + NBIN_A) { rel = 1; bid -= NBIN_P; nbin = NBIN_A; boff = NBIN_P; N = NAUTHOR; }
    else { rel = 2; bid -= NBIN_P + NBIN_A; nbin = NBIN_P; boff = NBIN_P + NBIN_A; N = NPAPER; }

    const int base = g_binbase[boff + bid];
    const int next = (bid + 1 < nbin) ? g_binbase[boff + bid + 1] : NEDGE;
    const int cnt  = next - base;
    const unsigned* bin = binned + (size_t)rel * NEDGE + base;
    int* row_ptr = sel3m(rel, rp0, rp1, rp2);
    int* csr     = sel3m(rel, c0, c1, c2);

    __shared__ int off[BIN_SIZE];
    __shared__ int lds[256];
    for (int i = threadIdx.x; i < BIN_SIZE; i += 256) off[i] = 0;
    __syncthreads();
    for (int i = threadIdx.x; i < cnt; i += 256)
        atomicAdd(&off[bin[i] >> 18], 1);
    __syncthreads();

    const int t  = threadIdx.x;
    const int i4 = t * 4;
    const int v0 = off[i4], v1 = off[i4 + 1], v2 = off[i4 + 2], v3 = off[i4 + 3];
    const int tsum = v0 + v1 + v2 + v3;
    lds[t] = tsum;
    __syncthreads();
    for (int o = 1; o < 256; o <<= 1) {
        const int x = (t >= o) ? lds[t - o] : 0;
        __syncthreads();
        lds[t] += x;
        __syncthreads();
    }
    const int run = lds[t] - tsum;
    const int ex0 = run, ex1 = ex0 + v0, ex2 = ex1 + v1, ex3 = ex2 + v2;
    off[i4] = ex0; off[i4 + 1] = ex1; off[i4 + 2] = ex2; off[i4 + 3] = ex3;
    const int d0g = bid * BIN_SIZE + i4;
    if (d0g     < N) row_ptr[d0g]     = base + ex0;
    if (d0g + 1 < N) row_ptr[d0g + 1] = base + ex1;
    if (d0g + 2 < N) row_ptr[d0g + 2] = base + ex2;
    if (d0g + 3 < N) row_ptr[d0g + 3] = base + ex3;
    __syncthreads();

    for (int i = threadIdx.x; i < cnt; i += 256) {
        const unsigned pk = bin[i];
        const int slot = atomicAdd(&off[pk >> 18], 1);
        csr[base + slot] = (int)(pk & 0x3FFFFu);
    }
}

// ---------------------------------------------------------------------------
// GATv2 aggregation, wave per dst node — PACKED:
//   lane = (half = lane>>5) x (cp = lane&31); channels 2cp,2cp+1.
//   Half h processes edge slots 2p+h -> one gather/exp/fma per TWO edges.
//   Head (32 ch) = one 16-lane DPP row -> reduce = pair-add + 4 DPP, no LDS.
// MODE 0: nw[d] = bias + result (bias-only for deg-0 rows)
// MODE 1: nw[d] += result (skip deg-0)
// ---------------------------------------------------------------------------
template <int MODE>
__global__ __launch_bounds__(256) void gat_dst(
    const int* __restrict__ row_ptr, const int* __restrict__ csr_src,
    const __hip_bfloat16* __restrict__ xl, const __hip_bfloat16* __restrict__ xr,
    const void* __restrict__ att, int att_off,
    const void* __restrict__ b1, int off1,
    const void* __restrict__ b2, int off2,    // b2 may be null (MODE 0 only)
    float* __restrict__ nw, int Nd, const int* __restrict__ flagp)
{
    __shared__ float satt[64];
    __shared__ float sbias[64];
    if (threadIdx.x < 64) {
        const int f32 = flagp[0];
        satt[threadIdx.x] = wireF(att, att_off + threadIdx.x, f32);
        if (MODE == 0) {
            float bv = wireF(b1, off1 + threadIdx.x, f32);
            if (b2) bv += wireF(b2, off2 + threadIdx.x, f32);
            sbias[threadIdx.x] = bv;
        }
    }
    __syncthreads();

    const int d    = blockIdx.x * 4 + (threadIdx.x >> 6);
    const int lane = threadIdx.x & 63;
    const int half = lane >> 5;               // edge-slot parity
    const int cp   = lane & 31;               // channel pair index
    if (d >= Nd) return;
    const int beg = row_ptr[d];
    const int end = row_ptr[d + 1];

    float* out2 = &nw[(size_t)d * 64 + 2 * cp];

    if (beg == end) {                         // no incident edges
        if (MODE == 0 && half == 0) {
            out2[0] = sbias[2 * cp];
            out2[1] = sbias[2 * cp + 1];
        }
        return;
    }

    const unsigned uxr = ((const unsigned*)xr)[(size_t)d * 32 + cp];
    const float xr0 = bf_lo(uxr), xr1 = bf_hi(uxr);
    const float a0 = satt[2 * cp], a1 = satt[2 * cp + 1];
    const unsigned* xlw = (const unsigned*)xl;

    float accx = 0.0f, accy = 0.0f, den = 0.0f;

    int chunk = beg;
    while (chunk < end) {
        const int cend = (chunk + 64 < end) ? (chunk + 64) : end;
        const int n    = cend - chunk;        // 1..64 edges this chunk
        const int npairs = (n + 1) >> 1;
        // cooperative index load: lane j holds csr_src[chunk + j] (clamped)
        const int lidx = csr_src[chunk + ((lane < n) ? lane : 0)];

        // prime 4 pair-slots (= 8 edges across the two halves)
        unsigned g0, g1, g2, g3;
        {
            const int s0 = __shfl(lidx, (0 + half) & 63, 64);
            const int s1 = __shfl(lidx, (2 + half) & 63, 64);
            const int s2 = __shfl(lidx, (4 + half) & 63, 64);
            const int s3 = __shfl(lidx, (6 + half) & 63, 64);
            g0 = xlw[(size_t)s0 * 32 + cp];
            g1 = xlw[(size_t)s1 * 32 + cp];
            g2 = xlw[(size_t)s2 * 32 + cp];
            g3 = xlw[(size_t)s3 * 32 + cp];
        }

        int base = 0;
        while (true) {
            const bool hn = base + 4 < npairs;
            unsigned h0 = 0, h1 = 0, h2 = 0, h3 = 0;
            if (hn) {                          // prefetch next 4 pair-slots
                const int t0 = __shfl(lidx, (2 * (base + 4) + half) & 63, 64);
                const int t1 = __shfl(lidx, (2 * (base + 5) + half) & 63, 64);
                const int t2 = __shfl(lidx, (2 * (base + 6) + half) & 63, 64);
                const int t3 = __shfl(lidx, (2 * (base + 7) + half) & 63, 64);
                h0 = xlw[(size_t)t0 * 32 + cp];
                h1 = xlw[(size_t)t1 * 32 + cp];
                h2 = xlw[(size_t)t2 * 32 + cp];
                h3 = xlw[(size_t)t3 * 32 + cp];
            }

            const float x00 = bf_lo(g0), x01 = bf_hi(g0);
            const float x10 = bf_lo(g1), x11 = bf_hi(g1);
            const float x20 = bf_lo(g2), x21 = bf_hi(g2);
            const float x30 = bf_lo(g3), x31 = bf_hi(g3);

            float v;
            float u0, u1, u2, u3;
            v = x00 + xr0; v = (v > 0.0f) ? v : 0.2f * v; u0 = v * a0;
            v = x01 + xr1; v = (v > 0.0f) ? v : 0.2f * v; u0 += v * a1;
            v = x10 + xr0; v = (v > 0.0f) ? v : 0.2f * v; u1 = v * a0;
            v = x11 + xr1; v = (v > 0.0f) ? v : 0.2f * v; u1 += v * a1;
            v = x20 + xr0; v = (v > 0.0f) ? v : 0.2f * v; u2 = v * a0;
            v = x21 + xr1; v = (v > 0.0f) ? v : 0.2f * v; u2 += v * a1;
            v = x30 + xr0; v = (v > 0.0f) ? v : 0.2f * v; u3 = v * a0;
            v = x31 + xr1; v = (v > 0.0f) ? v : 0.2f * v; u3 += v * a1;

            u0 = hs16(u0);                     // 4 DPP each, no LDS op
            u1 = hs16(u1);
            u2 = hs16(u2);
            u3 = hs16(u3);

            const int eb = 2 * base + half;
            const float e0 = (eb + 0 < n) ? __expf(u0) : 0.0f;
            const float e1 = (eb + 2 < n) ? __expf(u1) : 0.0f;
            const float e2 = (eb + 4 < n) ? __expf(u2) : 0.0f;
            const float e3 = (eb + 6 < n) ? __expf(u3) : 0.0f;

            accx += e0 * x00 + e1 * x10;
            accy += e0 * x01 + e1 * x11;
            accx += e2 * x20 + e3 * x30;
            accy += e2 * x21 + e3 * x31;
            den  += (e0 + e1) + (e2 + e3);

            if (!hn) break;
            g0 = h0; g1 = h1; g2 = h2; g3 = h3;
            base += 4;
        }
        chunk = cend;
    }

    // combine the two halves (each accumulated its own edge parity)
    accx += __shfl_xor(accx, 32, 64);
    accy += __shfl_xor(accy, 32, 64);
    den  += __shfl_xor(den,  32, 64);

    if (half == 0) {
        const float rx = accx / den;
        const float ry = accy / den;
        if (MODE == 0) {
            out2[0] = sbias[2 * cp]     + rx;
            out2[1] = sbias[2 * cp + 1] + ry;
        } else {
            out2[0] += rx;
            out2[1] += ry;
        }
    }
}

// ---------------------------------------------------------------------------
// LayerNorm(64) + affine + ReLU for BOTH node types in one launch.
// One wave per row; writes internal bf16 h.
// ---------------------------------------------------------------------------
__global__ __launch_bounds__(256) void ln_relu2(
    const float* __restrict__ nb_p, const float* __restrict__ nb_a,
    const void* __restrict__ g, int goff_p, int goff_a,
    const void* __restrict__ b, int boff_p, int boff_a,
    __hip_bfloat16* __restrict__ h_p, __hip_bfloat16* __restrict__ h_a,
    const int* __restrict__ flagp)
{
    int row = blockIdx.x * 4 + (threadIdx.x >> 6);
    const int c = threadIdx.x & 63;
    const int f32 = flagp[0];

    const float* nb; __hip_bfloat16* h; int goff, boff;
    if (row < NPAPER) {                     // NPAPER % 4 == 0: uniform block
        nb = nb_p; h = h_p; goff = goff_p; boff = boff_p;
    } else {
        row -= NPAPER;
        if (row >= NAUTHOR) return;
        nb = nb_a; h = h_a; goff = goff_a; boff = boff_a;
    }

    const float v = nb[(size_t)row * 64 + c];
    float s = v;
#pragma unroll
    for (int o = 32; o > 0; o >>= 1) s += __shfl_xor(s, o, 64);
    const float mu = s * (1.0f / 64.0f);
    const float dd = v - mu;
    float q = dd * dd;
#pragma unroll
    for (int o = 32; o > 0; o >>= 1) q += __shfl_xor(q, o, 64);
    const float var = q * (1.0f / 64.0f);
    float y = dd * rsqrtf(var + 1e-5f) * wireF(g, goff + c, f32)
            + wireF(b, boff + c, f32);
    y = (y < 0.0f) ? 0.0f : y;                  // NaN propagates
    h[(size_t)row * 64 + c] = __float2bfloat16(y);
}

// ---------------------------------------------------------------------------
extern "C" void kernel_launch(void* const* d_in, const int* in_sizes, int n_in,
                              void* d_out, int out_size, void* d_ws, size_t ws_size,
                              hipStream_t stream)
{
    const void* x_p   = d_in[0];
    const void* x_a   = d_in[1];
    const int* e_ws_s = (const int*)d_in[2];
    const int* e_ws_d = (const int*)d_in[3];
    const int* e_rv_s = (const int*)d_in[4];
    const int* e_rv_d = (const int*)d_in[5];
    const int* e_ci_s = (const int*)d_in[6];
    const int* e_ci_d = (const int*)d_in[7];
    const void* inW_p = d_in[8];
    const void* inW_a = d_in[9];
    const void* Wl    = d_in[10];
    const void* bl    = d_in[11];
    const void* Wr    = d_in[12];
    const void* br    = d_in[13];
    const void* att   = d_in[14];
    const void* gbias = d_in[15];
    const void* lng   = d_in[16];
    const void* lnb   = d_in[17];
    const void* oWp   = d_in[18];
    const void* obp   = d_in[19];
    const void* oWa   = d_in[20];
    const void* oba   = d_in[21];

    char* p = (char*)d_ws;
    auto carve = [&](size_t bytes) -> char* {
        char* r = p;
        p += (bytes + 255) & ~(size_t)255;
        return r;
    };
    int* flag = (int*)carve(256);
    __hip_bfloat16* h_p = (__hip_bfloat16*)carve((size_t)NPAPER  * 64 * 2);
    __hip_bfloat16* h_a = (__hip_bfloat16*)carve((size_t)NAUTHOR * 64 * 2);
    __hip_bfloat16* xl  = (__hip_bfloat16*)carve((size_t)NPAPER * 64 * 2);
    __hip_bfloat16* xr  = (__hip_bfloat16*)carve((size_t)NPAPER * 64 * 2);
    float* new_p = (float*)carve((size_t)NPAPER  * 64 * 4);
    float* new_a = (float*)carve((size_t)NAUTHOR * 64 * 4);
    int *csr_src[3], *row_ptr[3];
    for (int r = 0; r < 3; r++) {
        csr_src[r] = (int*)carve((size_t)NEDGE * 4);
        row_ptr[r] = (int*)carve(((size_t)NPAPER + 1) * 4);
    }
    unsigned* binned = (unsigned*)carve((size_t)3 * NEDGE * 4);
    int* g_bincnt  = (int*)carve(NBIN_TOT * 4);
    int* g_binbase = (int*)carve(NBIN_TOT * 4);
    int* g_binres  = (int*)carve(NBIN_TOT * 4);

    detect_mode<<<dim3(1), dim3(64), 0, stream>>>((const unsigned*)lng, flag);

    // ---- binned CSR build, all 3 relations (reused by both layers) ----
    (void)hipMemsetAsync(g_bincnt, 0, NBIN_TOT * 4, stream);
    csr_count<<<dim3(3 * NBLK_BIN), dim3(256), 0, stream>>>(
        e_ws_d, e_rv_d, e_ci_d, g_bincnt);
    csr_binscan<<<dim3(1), dim3(256), 0, stream>>>(
        g_bincnt, g_binbase, g_binres, row_ptr[0], row_ptr[1], row_ptr[2]);
    csr_binscatter<<<dim3(3 * NBLK_BIN), dim3(256), 0, stream>>>(
        e_ws_s, e_rv_s, e_ci_s, e_ws_d, e_rv_d, e_ci_d, g_binres, binned);
    csr_build<<<dim3(NBIN_TOT), dim3(256), 0, stream>>>(
        binned, g_binbase, row_ptr[0], row_ptr[1], row_ptr[2],
        csr_src[0], csr_src[1], csr_src[2]);

    // ---- input projections (one launch, 2 jobs): h = x @ inW ----
    gemm256<128, 0, true><<<dim3(NB256_P + NB256_A), dim3(256), 0, stream>>>(
        x_p, inW_p, 0, nullptr, 0, h_p, NPAPER, 0, NB256_P,
        x_a, inW_a, 0, nullptr, 0, h_a, NAUTHOR, 0, flag);

    for (int l = 0; l < 2; l++) {
        const __hip_bfloat16* hs[3] = { h_a, h_p, h_p };   // source type
        const int             Ns[3] = { NAUTHOR, NPAPER, NPAPER };
        const int             Bs[3] = { NB256_A, NB256_P, NB256_P };
        const __hip_bfloat16* hd[3] = { h_p, h_a, h_p };   // dst type
        const int             Nd[3] = { NPAPER, NAUTHOR, NPAPER };
        const int             Bd[3] = { NB256_P, NB256_A, NB256_P };
        float* nb[3] = { new_p, new_a, new_p };

        for (int r = 0; r < 3; r++) {
            const int wo = (l * 3 + r) * 64 * 64;
            const int bo = (l * 3 + r) * 64;
            // xl and xr in ONE launch (2 jobs)
            gemm256<64, 0, false><<<dim3(Bs[r] + Bd[r]), dim3(256), 0, stream>>>(
                hs[r], Wl, wo, bl, bo, xl, Ns[r], 0, Bs[r],
                hd[r], Wr, wo, br, bo, xr, Nd[r], 0, flag);
            if (r == 0) {        // writes -> paper: WRITE, bias = g[l,0]+g[l,2]
                gat_dst<0><<<dim3((Nd[r] + 3) / 4), dim3(256), 0, stream>>>(
                    row_ptr[r], csr_src[r], xl, xr, att, bo,
                    gbias, (l * 3 + 0) * 64, gbias, (l * 3 + 2) * 64,
                    nb[r], Nd[r], flag);
            } else if (r == 1) { // rev -> author: WRITE, bias = g[l,1]
                gat_dst<0><<<dim3((Nd[r] + 3) / 4), dim3(256), 0, stream>>>(
                    row_ptr[r], csr_src[r], xl, xr, att, bo,
                    gbias, (l * 3 + 1) * 64, nullptr, 0,
                    nb[r], Nd[r], flag);
            } else {             // cites -> paper: ACCUMULATE
                gat_dst<1><<<dim3((Nd[r] + 3) / 4), dim3(256), 0, stream>>>(
                    row_ptr[r], csr_src[r], xl, xr, att, bo,
                    nullptr, 0, nullptr, 0,
                    nb[r], Nd[r], flag);
            }
        }

        ln_relu2<<<dim3((NPAPER + NAUTHOR) / 4), dim3(256), 0, stream>>>(
            new_p, new_a,
            lng, (l * 2 + 0) * 64, (l * 2 + 1) * 64,
            lnb, (l * 2 + 0) * 64, (l * 2 + 1) * 64,
            h_p, h_a, flag);
    }

    // ---- output projections (one launch, 2 jobs) into d_out ----
    gemm256<64, 2, false><<<dim3(NB256_P + NB256_A), dim3(256), 0, stream>>>(
        h_p, oWp, 0, obp, 0, d_out, NPAPER, 0, NB256_P,
        h_a, oWa, 0, oba, 0, d_out, NAUTHOR, NPAPER, flag);
}